// Round 1
// baseline (735.209 us; speedup 1.0000x reference)
//
#include <hip/hip_runtime.h>
#include <hip/hip_bf16.h>

// ============================================================================
// AttentionHead (B=8,S=4096,D=1024,DK=64), fp32 in/out — MI355X gfx950
// Precision: split-bf16 (hi+lo) x 3-product MFMA => ~fp32 accuracy
//   (dropped lo*lo ~2^-18 rel).  CDNA4 has no fp32-input MFMA.
// K0 splitw : W(fp32 [192][1024]) -> bf16 hi/lo
// K1 proj   : Q,K -> [b][s][64] hi/lo ; V -> transposed [b][64][s] hi/lo
// K2 attn   : flash, QB=KVB=64, 2 waves x (32 q-rows), 32x32x16 bf16 MFMA,
//             fp32 online softmax, grid reverse-sorted by qb (balance).
// All LDS tiles: [rows][64] bf16, pitch 128B, XOR swizzle ^((row&7)<<4)
// (row-major 128B rows are otherwise a 32-way bank conflict on ds_read_b128).
// ============================================================================

typedef __attribute__((ext_vector_type(8)))  short   short8;
typedef __attribute__((ext_vector_type(4)))  float   f32x4;
typedef __attribute__((ext_vector_type(16))) float   f32x16;
typedef __attribute__((ext_vector_type(4)))  unsigned short ushort4v;

#define DEV static __device__ __forceinline__

constexpr int SEQ    = 4096;
constexpr int DMODEL = 1024;
constexpr int DHEAD  = 64;
constexpr float SM_SCALE = 0.03125f;   // 1024^-0.5  (reference scales by d_model!)
constexpr float LOG2E    = 1.44269504088896340736f;
constexpr float NEG_BIG  = -3.0e38f;   // avoid inf-inf NaN paths

DEV unsigned short f2bf(float x) {           // fp32 -> bf16 RNE
    union { float f; unsigned u; } v; v.f = x;
    unsigned r = v.u + 0x7fffu + ((v.u >> 16) & 1u);
    return (unsigned short)(r >> 16);
}
DEV float bf2f(unsigned short h) {
    union { unsigned u; float f; } v; v.u = ((unsigned)h) << 16;
    return v.f;
}
// byte address inside a [rows][64]bf16 tile (pitch 128B) with XOR swizzle
DEV int swz(int row, int off) { return row * 128 + (off ^ ((row & 7) << 4)); }

// ---------------------------------------------------------------- kernel 0 --
__global__ void splitw_kernel(const float* __restrict__ wQ,
                              const float* __restrict__ wK,
                              const float* __restrict__ wV,
                              unsigned short* __restrict__ WH,
                              unsigned short* __restrict__ WL)
{
    int t  = blockIdx.x * 256 + threadIdx.x;   // 49152 float4 chunks, exact
    int fl = t * 4;
    const float* src = (fl < 65536) ? wQ : (fl < 131072 ? wK : wV);
    float4 v = *(const float4*)(src + (fl & 65535));
    float vv[4] = {v.x, v.y, v.z, v.w};
    ushort4v h, l;
    #pragma unroll
    for (int j = 0; j < 4; j++) {
        unsigned short hh = f2bf(vv[j]);
        h[j] = hh;
        l[j] = f2bf(vv[j] - bf2f(hh));
    }
    *(ushort4v*)(WH + fl) = h;
    *(ushort4v*)(WL + fl) = l;
}

// ---------------------------------------------------------------- kernel 1 --
// M-block 64 rows; 4 waves, wave w = 64 rows x cols [48w,48w+48); K-step 64.
__global__ __launch_bounds__(256, 2)
void proj_kernel(const float* __restrict__ x,
                 const unsigned short* __restrict__ WH,
                 const unsigned short* __restrict__ WL,
                 unsigned short* __restrict__ QH, unsigned short* __restrict__ QL,
                 unsigned short* __restrict__ KH, unsigned short* __restrict__ KL,
                 unsigned short* __restrict__ VTH, unsigned short* __restrict__ VTL)
{
    __shared__ unsigned char sm[65536];
    constexpr int XHo = 0, XLo = 8192, WHo = 16384, WLo = 40960;
    const int tid  = threadIdx.x;
    const int lane = tid & 63;
    const int w    = tid >> 6;
    const int m0   = blockIdx.x * 64;          // global row base (b*4096+s0)
    const int b    = m0 >> 12;
    const int s0   = m0 & 4095;

    f32x4 acc[4][3];
    #pragma unroll
    for (int i = 0; i < 4; i++)
        #pragma unroll
        for (int j = 0; j < 3; j++)
            #pragma unroll
            for (int r = 0; r < 4; r++) acc[i][j][r] = 0.f;

    for (int k0 = 0; k0 < DMODEL; k0 += 64) {
        __syncthreads();
        // stage x 64x64 fp32 -> hi/lo bf16 (1024 float4 chunks / 256 thr)
        #pragma unroll
        for (int i = 0; i < 4; i++) {
            int c = tid + i * 256;
            int row = c >> 4, c16 = c & 15;
            float4 v = *(const float4*)(x + (size_t)(m0 + row) * DMODEL + k0 + c16 * 4);
            float vv[4] = {v.x, v.y, v.z, v.w};
            ushort4v h, l;
            #pragma unroll
            for (int j = 0; j < 4; j++) {
                unsigned short hh = f2bf(vv[j]);
                h[j] = hh;
                l[j] = f2bf(vv[j] - bf2f(hh));
            }
            int ba = swz(row, c16 * 8);
            *(ushort4v*)(sm + XHo + ba) = h;
            *(ushort4v*)(sm + XLo + ba) = l;
        }
        // stage W slice 192x64 (hi/lo, 1536 16B chunks / 256 thr)
        #pragma unroll
        for (int i = 0; i < 6; i++) {
            int c = tid + i * 256;
            int row = c >> 3, c8 = c & 7;
            int ba = swz(row, c8 * 16);
            *(uint4*)(sm + WHo + ba) = *(const uint4*)(WH + (size_t)row * DMODEL + k0 + c8 * 8);
            *(uint4*)(sm + WLo + ba) = *(const uint4*)(WL + (size_t)row * DMODEL + k0 + c8 * 8);
        }
        __syncthreads();
        #pragma unroll
        for (int ks = 0; ks < 2; ks++) {
            short8 ah[4], al[4];
            #pragma unroll
            for (int ms = 0; ms < 4; ms++) {
                int row = ms * 16 + (lane & 15);
                int off = ks * 64 + ((lane >> 4) << 4);
                ah[ms] = *(const short8*)(sm + XHo + swz(row, off));
                al[ms] = *(const short8*)(sm + XLo + swz(row, off));
            }
            #pragma unroll
            for (int ns = 0; ns < 3; ns++) {
                int row = w * 48 + ns * 16 + (lane & 15);
                int off = ks * 64 + ((lane >> 4) << 4);
                short8 bh = *(const short8*)(sm + WHo + swz(row, off));
                short8 bl = *(const short8*)(sm + WLo + swz(row, off));
                #pragma unroll
                for (int ms = 0; ms < 4; ms++) {
                    acc[ms][ns] = __builtin_amdgcn_mfma_f32_16x16x32_bf16(ah[ms], bh, acc[ms][ns], 0, 0, 0);
                    acc[ms][ns] = __builtin_amdgcn_mfma_f32_16x16x32_bf16(ah[ms], bl, acc[ms][ns], 0, 0, 0);
                    acc[ms][ns] = __builtin_amdgcn_mfma_f32_16x16x32_bf16(al[ms], bh, acc[ms][ns], 0, 0, 0);
                }
            }
        }
    }
    // epilogue: C/D 16x16 layout: col = lane&15, row = (lane>>4)*4 + r  [m89]
    #pragma unroll
    for (int ms = 0; ms < 4; ms++) {
        #pragma unroll
        for (int ns = 0; ns < 3; ns++) {
            int c   = w * 48 + ns * 16 + (lane & 15);
            int mat = c >> 6;                 // tile is 16-aligned: uniform
            int dk  = c & 63;
            int rb  = ms * 16 + ((lane >> 4) << 2);
            if (mat == 0) {
                #pragma unroll
                for (int r = 0; r < 4; r++) {
                    float v = acc[ms][ns][r];
                    size_t o = (size_t)(m0 + rb + r) * DHEAD + dk;
                    unsigned short hh = f2bf(v);
                    QH[o] = hh; QL[o] = f2bf(v - bf2f(hh));
                }
            } else if (mat == 1) {
                #pragma unroll
                for (int r = 0; r < 4; r++) {
                    float v = acc[ms][ns][r];
                    size_t o = (size_t)(m0 + rb + r) * DHEAD + dk;
                    unsigned short hh = f2bf(v);
                    KH[o] = hh; KL[o] = f2bf(v - bf2f(hh));
                }
            } else {                          // V stored transposed [b][dk][s]
                ushort4v h, l;
                #pragma unroll
                for (int r = 0; r < 4; r++) {
                    float v = acc[ms][ns][r];
                    unsigned short hh = f2bf(v);
                    h[r] = hh; l[r] = f2bf(v - bf2f(hh));
                }
                size_t o = ((size_t)(b * DHEAD + dk)) * SEQ + s0 + rb;
                *(ushort4v*)(VTH + o) = h;
                *(ushort4v*)(VTL + o) = l;
            }
        }
    }
}

// ---------------------------------------------------------------- kernel 2 --
// 32x32x16 bf16 MFMA. C/D layout: col=lane&31, row=(r&3)+8*(r>>2)+4*(lane>>5).
__global__ __launch_bounds__(128, 1)
void attn_kernel(const unsigned short* __restrict__ QH, const unsigned short* __restrict__ QL,
                 const unsigned short* __restrict__ KH, const unsigned short* __restrict__ KL,
                 const unsigned short* __restrict__ VTH, const unsigned short* __restrict__ VTL,
                 float* __restrict__ out)
{
    __shared__ unsigned char sm[65536];
    constexpr int QHo = 0, QLo = 8192, KHo = 16384, KLo = 24576,
                  VHo = 32768, VLo = 40960, PHo = 49152, PLo = 57344;
    const int tid  = threadIdx.x;
    const int lane = tid & 63;
    const int w    = tid >> 6;
    const int idx  = blockIdx.x;
    const int qb   = 63 - (idx >> 3);      // reverse order: longest blocks first
    const int b    = idx & 7;
    const int q0   = qb * 64;

    // stage Q tile (hi/lo), then hoist A-frags to registers for the whole block
    #pragma unroll
    for (int i = 0; i < 4; i++) {
        int c = tid + i * 128;
        int row = c >> 3, c8 = c & 7;
        size_t g = (size_t)(b * SEQ + q0 + row) * DHEAD + c8 * 8;
        int ba = swz(row, c8 * 16);
        *(uint4*)(sm + QHo + ba) = *(const uint4*)(QH + g);
        *(uint4*)(sm + QLo + ba) = *(const uint4*)(QL + g);
    }
    __syncthreads();
    short8 qh[4], ql[4];
    #pragma unroll
    for (int ks = 0; ks < 4; ks++) {
        int row = w * 32 + (lane & 31);
        int off = ks * 32 + ((lane >> 5) << 4);
        qh[ks] = *(const short8*)(sm + QHo + swz(row, off));
        ql[ks] = *(const short8*)(sm + QLo + swz(row, off));
    }

    f32x16 oacc[2];
    float m_r[16], l_r[16];
    #pragma unroll
    for (int r = 0; r < 16; r++) { m_r[r] = NEG_BIG; l_r[r] = 0.f; oacc[0][r] = 0.f; oacc[1][r] = 0.f; }

    for (int t = 0; t <= qb; t++) {
        const int kv0 = t * 64;
        __syncthreads();
        #pragma unroll
        for (int i = 0; i < 4; i++) {
            int c = tid + i * 128;
            int row = c >> 3, c8 = c & 7;
            size_t gk = (size_t)(b * SEQ + kv0 + row) * DHEAD + c8 * 8;
            size_t gv = (size_t)(b * DHEAD + row) * SEQ + kv0 + c8 * 8;
            int ba = swz(row, c8 * 16);
            *(uint4*)(sm + KHo + ba) = *(const uint4*)(KH + gk);
            *(uint4*)(sm + KLo + ba) = *(const uint4*)(KL + gk);
            *(uint4*)(sm + VHo + ba) = *(const uint4*)(VTH + gv);
            *(uint4*)(sm + VLo + ba) = *(const uint4*)(VTL + gv);
        }
        __syncthreads();

        // ---- S = Q K^T  (wave: 32 q-rows x 64 kv) ----
        f32x16 sacc[2];
        #pragma unroll
        for (int r = 0; r < 16; r++) { sacc[0][r] = 0.f; sacc[1][r] = 0.f; }
        #pragma unroll
        for (int ks = 0; ks < 4; ks++) {
            #pragma unroll
            for (int sub = 0; sub < 2; sub++) {
                int row = sub * 32 + (lane & 31);
                int off = ks * 32 + ((lane >> 5) << 4);
                short8 kh = *(const short8*)(sm + KHo + swz(row, off));
                short8 kl = *(const short8*)(sm + KLo + swz(row, off));
                sacc[sub] = __builtin_amdgcn_mfma_f32_32x32x16_bf16(qh[ks], kh, sacc[sub], 0, 0, 0);
                sacc[sub] = __builtin_amdgcn_mfma_f32_32x32x16_bf16(qh[ks], kl, sacc[sub], 0, 0, 0);
                sacc[sub] = __builtin_amdgcn_mfma_f32_32x32x16_bf16(ql[ks], kh, sacc[sub], 0, 0, 0);
            }
        }

        // ---- online softmax (fp32), in-place into sacc ----
        const bool diag = (t == qb);
        #pragma unroll
        for (int r = 0; r < 16; r++) {
            float s0v = sacc[0][r] * SM_SCALE;
            float s1v = sacc[1][r] * SM_SCALE;
            if (diag) {
                int qi = w * 32 + (r & 3) + ((r >> 2) << 3) + ((lane >> 5) << 2);
                int ci = lane & 31;
                if (ci > qi)      s0v = NEG_BIG;
                if (32 + ci > qi) s1v = NEG_BIG;
            }
            float v = fmaxf(s0v, s1v);
            v = fmaxf(v, __shfl_xor(v, 1, 64));
            v = fmaxf(v, __shfl_xor(v, 2, 64));
            v = fmaxf(v, __shfl_xor(v, 4, 64));
            v = fmaxf(v, __shfl_xor(v, 8, 64));
            v = fmaxf(v, __shfl_xor(v, 16, 64));
            float mn = fmaxf(m_r[r], v);
            float al = __builtin_amdgcn_exp2f((m_r[r] - mn) * LOG2E);
            m_r[r] = mn;
            float p0 = __builtin_amdgcn_exp2f((s0v - mn) * LOG2E);
            float p1 = __builtin_amdgcn_exp2f((s1v - mn) * LOG2E);
            sacc[0][r] = p0; sacc[1][r] = p1;
            float rs = p0 + p1;
            rs += __shfl_xor(rs, 1, 64);
            rs += __shfl_xor(rs, 2, 64);
            rs += __shfl_xor(rs, 4, 64);
            rs += __shfl_xor(rs, 8, 64);
            rs += __shfl_xor(rs, 16, 64);
            l_r[r] = l_r[r] * al + rs;
            oacc[0][r] *= al;
            oacc[1][r] *= al;
        }

        // ---- P -> wave-private LDS (hi/lo) ----
        #pragma unroll
        for (int sub = 0; sub < 2; sub++) {
            #pragma unroll
            for (int r = 0; r < 16; r++) {
                int qr  = (r & 3) + ((r >> 2) << 3) + ((lane >> 5) << 2);
                int col = sub * 32 + (lane & 31);
                int ba  = swz(qr, col * 2);
                float p = sacc[sub][r];
                unsigned short hh = f2bf(p);
                *(unsigned short*)(sm + PHo + w * 4096 + ba) = hh;
                *(unsigned short*)(sm + PLo + w * 4096 + ba) = f2bf(p - bf2f(hh));
            }
        }

        // ---- O += P V  (B-operand from transposed V tile) ----
        #pragma unroll
        for (int ks = 0; ks < 4; ks++) {
            int prow = lane & 31;
            int poff = ks * 32 + ((lane >> 5) << 4);
            short8 pah = *(const short8*)(sm + PHo + w * 4096 + swz(prow, poff));
            short8 pal = *(const short8*)(sm + PLo + w * 4096 + swz(prow, poff));
            #pragma unroll
            for (int dsub = 0; dsub < 2; dsub++) {
                int vrow = dsub * 32 + (lane & 31);
                short8 vh = *(const short8*)(sm + VHo + swz(vrow, poff));
                short8 vl = *(const short8*)(sm + VLo + swz(vrow, poff));
                oacc[dsub] = __builtin_amdgcn_mfma_f32_32x32x16_bf16(pah, vh, oacc[dsub], 0, 0, 0);
                oacc[dsub] = __builtin_amdgcn_mfma_f32_32x32x16_bf16(pah, vl, oacc[dsub], 0, 0, 0);
                oacc[dsub] = __builtin_amdgcn_mfma_f32_32x32x16_bf16(pal, vh, oacc[dsub], 0, 0, 0);
            }
        }
    }

    // ---- epilogue: O = acc / l ----
    #pragma unroll
    for (int dsub = 0; dsub < 2; dsub++) {
        #pragma unroll
        for (int r = 0; r < 16; r++) {
            int qr = (r & 3) + ((r >> 2) << 3) + ((lane >> 5) << 2);
            size_t o = (size_t)(b * SEQ + q0 + w * 32 + qr) * DHEAD + dsub * 32 + (lane & 31);
            out[o] = oacc[dsub][r] / l_r[r];
        }
    }
}

// ------------------------------------------------------------------- launch --
extern "C" void kernel_launch(void* const* d_in, const int* in_sizes, int n_in,
                              void* d_out, int out_size, void* d_ws, size_t ws_size,
                              hipStream_t stream)
{
    const float* x  = (const float*)d_in[0];
    const float* wQ = (const float*)d_in[1];
    const float* wK = (const float*)d_in[2];
    const float* wV = (const float*)d_in[3];
    float* out = (float*)d_out;

    // workspace layout (ushorts): total ~26 MB
    unsigned short* p   = (unsigned short*)d_ws;
    unsigned short* WH  = p; p += 192 * 1024;
    unsigned short* WL  = p; p += 192 * 1024;
    unsigned short* QHp = p; p += 8 * 4096 * 64;
    unsigned short* QLp = p; p += 8 * 4096 * 64;
    unsigned short* KHp = p; p += 8 * 4096 * 64;
    unsigned short* KLp = p; p += 8 * 4096 * 64;
    unsigned short* VTH = p; p += 8 * 4096 * 64;
    unsigned short* VTL = p; p += 8 * 4096 * 64;

    splitw_kernel<<<dim3(192), dim3(256), 0, stream>>>(wQ, wK, wV, WH, WL);
    proj_kernel<<<dim3(512), dim3(256), 0, stream>>>(x, WH, WL, QHp, QLp, KHp, KLp, VTH, VTL);
    attn_kernel<<<dim3(512), dim3(128), 0, stream>>>(QHp, QLp, KHp, KLp, VTH, VTL, out);
}

// Round 2
// 446.109 us; speedup vs baseline: 1.6480x; 1.6480x over previous
//
#include <hip/hip_runtime.h>
#include <hip/hip_bf16.h>

// ============================================================================
// AttentionHead (B=8,S=4096,D=1024,DK=64), fp32 in/out — MI355X gfx950
// R2: split-K flash (1280 blocks, <=16 KV tiles each) + global_load_lds
//     staging from pre-swizzled global layouts + combine kernel.
// Precision: split-bf16 (hi+lo) x 3-product MFMA => ~fp32 accuracy.
// K0 splitw : W(fp32 [192][1024]) -> bf16 hi/lo, k-tiled swizzled layout
// K1 proj   : Q,K,V; K/V written in attn-tile swizzled layouts
// K2 attn   : flash chunk, QB=64, KVB=64, 2 waves, 32x32x16 bf16 MFMA
// K3 combine: merge partial (O,m,l) chunks for qb>=16
// LDS tiles: [rows][64] bf16, pitch 128B, XOR swizzle ^((row&7)<<4).
// Workspace use: ~58 MB.
// ============================================================================

typedef __attribute__((ext_vector_type(8)))  short   short8;
typedef __attribute__((ext_vector_type(4)))  float   f32x4;
typedef __attribute__((ext_vector_type(16))) float   f32x16;
typedef __attribute__((ext_vector_type(4)))  unsigned short ushort4v;

#define DEV static __device__ __forceinline__

constexpr int SEQ    = 4096;
constexpr int DMODEL = 1024;
constexpr int DHEAD  = 64;
constexpr float SM_SCALE = 0.03125f;   // 1024^-0.5 (reference scales by d_model)
constexpr float LOG2E    = 1.44269504088896340736f;
constexpr float NEG_BIG  = -3.0e38f;

DEV unsigned short f2bf(float x) {           // fp32 -> bf16 RNE
    union { float f; unsigned u; } v; v.f = x;
    unsigned r = v.u + 0x7fffu + ((v.u >> 16) & 1u);
    return (unsigned short)(r >> 16);
}
DEV float bf2f(unsigned short h) {
    union { unsigned u; float f; } v; v.u = ((unsigned)h) << 16;
    return v.f;
}
// byte address inside a [rows][64]bf16 tile (pitch 128B) with XOR swizzle
DEV int swz(int row, int off) { return row * 128 + (off ^ ((row & 7) << 4)); }

// async 16B global -> LDS (linear dest; source layouts are pre-swizzled)
DEV void gload16(const unsigned short* g, unsigned char* l) {
    __builtin_amdgcn_global_load_lds(
        (const __attribute__((address_space(1))) unsigned int*)g,
        (__attribute__((address_space(3))) unsigned int*)l, 16, 0, 0);
}

// ---------------------------------------------------------------- kernel 0 --
// W -> bf16 hi/lo in k-tiled swizzled layout: WHs[kt][row][c ^ ((row&7)<<3)]
__global__ void splitw_kernel(const float* __restrict__ wQ,
                              const float* __restrict__ wK,
                              const float* __restrict__ wV,
                              unsigned short* __restrict__ WHs,
                              unsigned short* __restrict__ WLs)
{
    int t  = blockIdx.x * 256 + threadIdx.x;   // 49152 float4 chunks, exact
    int fl = t * 4;
    int row = fl >> 10;                         // 0..191 (Q,K,V stacked)
    int k   = fl & 1023;
    const float* src = (row < 64) ? wQ : (row < 128 ? wK : wV);
    float4 v = *(const float4*)(src + (row & 63) * 1024 + k);
    float vv[4] = {v.x, v.y, v.z, v.w};
    ushort4v h, l;
    #pragma unroll
    for (int j = 0; j < 4; j++) {
        unsigned short hh = f2bf(vv[j]);
        h[j] = hh;
        l[j] = f2bf(vv[j] - bf2f(hh));
    }
    int kt = k >> 6, c = k & 63;               // c is 4-aligned; XOR keeps 4 contiguous
    size_t u = (size_t)kt * 12288 + row * 64 + (c ^ ((row & 7) << 3));
    *(ushort4v*)(WHs + u) = h;
    *(ushort4v*)(WLs + u) = l;
}

// ---------------------------------------------------------------- kernel 1 --
// M-block 64 rows; 4 waves, wave w = 64 rows x cols [48w,48w+48); K-step 64.
// W staged via global_load_lds (pre-swizzled); x staged via VGPR (needs split).
__global__ __launch_bounds__(256, 2)
void proj_kernel(const float* __restrict__ x,
                 const unsigned short* __restrict__ WHs,
                 const unsigned short* __restrict__ WLs,
                 unsigned short* __restrict__ QH,  unsigned short* __restrict__ QL,
                 unsigned short* __restrict__ KHs, unsigned short* __restrict__ KLs,
                 unsigned short* __restrict__ VHs, unsigned short* __restrict__ VLs)
{
    __shared__ unsigned char sm[65536];
    constexpr int XHo = 0, XLo = 8192, WHo = 16384, WLo = 40960;
    const int tid  = threadIdx.x;
    const int lane = tid & 63;
    const int w    = tid >> 6;
    const int m0   = blockIdx.x * 64;          // global row base (b*4096+s0)
    const int b    = m0 >> 12;
    const int s0   = m0 & 4095;
    const int tile = s0 >> 6;                  // this block covers exactly 1 kv tile

    f32x4 acc[4][3];
    #pragma unroll
    for (int i = 0; i < 4; i++)
        #pragma unroll
        for (int j = 0; j < 3; j++)
            #pragma unroll
            for (int r = 0; r < 4; r++) acc[i][j][r] = 0.f;

    for (int k0 = 0; k0 < DMODEL; k0 += 64) {
        __syncthreads();
        // stage x 64x64 fp32 -> hi/lo bf16 (1024 float4 chunks / 256 thr)
        #pragma unroll
        for (int i = 0; i < 4; i++) {
            int c = tid + i * 256;
            int row = c >> 4, c16 = c & 15;
            float4 v = *(const float4*)(x + (size_t)(m0 + row) * DMODEL + k0 + c16 * 4);
            float vv[4] = {v.x, v.y, v.z, v.w};
            ushort4v h, l;
            #pragma unroll
            for (int j = 0; j < 4; j++) {
                unsigned short hh = f2bf(vv[j]);
                h[j] = hh;
                l[j] = f2bf(vv[j] - bf2f(hh));
            }
            int ba = swz(row, c16 * 8);
            *(ushort4v*)(sm + XHo + ba) = h;
            *(ushort4v*)(sm + XLo + ba) = l;
        }
        // stage W slice 192x64 hi/lo via async global->LDS (24 KB each)
        {
            const size_t wb = (size_t)(k0 >> 6) * 12288;
            #pragma unroll
            for (int i = 0; i < 6; i++) {
                int j  = w * 6 + i;
                int go = j * 512 + lane * 8;     // ushorts
                gload16(WHs + wb + go, sm + WHo + j * 1024);
                gload16(WLs + wb + go, sm + WLo + j * 1024);
            }
        }
        __syncthreads();
        #pragma unroll
        for (int ks = 0; ks < 2; ks++) {
            short8 ah[4], al[4];
            #pragma unroll
            for (int ms = 0; ms < 4; ms++) {
                int row = ms * 16 + (lane & 15);
                int off = ks * 64 + ((lane >> 4) << 4);
                ah[ms] = *(const short8*)(sm + XHo + swz(row, off));
                al[ms] = *(const short8*)(sm + XLo + swz(row, off));
            }
            #pragma unroll
            for (int ns = 0; ns < 3; ns++) {
                int row = w * 48 + ns * 16 + (lane & 15);
                int off = ks * 64 + ((lane >> 4) << 4);
                short8 bh = *(const short8*)(sm + WHo + swz(row, off));
                short8 bl = *(const short8*)(sm + WLo + swz(row, off));
                #pragma unroll
                for (int ms = 0; ms < 4; ms++) {
                    acc[ms][ns] = __builtin_amdgcn_mfma_f32_16x16x32_bf16(ah[ms], bh, acc[ms][ns], 0, 0, 0);
                    acc[ms][ns] = __builtin_amdgcn_mfma_f32_16x16x32_bf16(ah[ms], bl, acc[ms][ns], 0, 0, 0);
                    acc[ms][ns] = __builtin_amdgcn_mfma_f32_16x16x32_bf16(al[ms], bh, acc[ms][ns], 0, 0, 0);
                }
            }
        }
    }
    // epilogue: C/D 16x16 layout: col = lane&15, row = (lane>>4)*4 + r
    #pragma unroll
    for (int ms = 0; ms < 4; ms++) {
        #pragma unroll
        for (int ns = 0; ns < 3; ns++) {
            int c   = w * 48 + ns * 16 + (lane & 15);
            int mat = c >> 6;                 // 0=Q 1=K 2=V (uniform per ns)
            int dk  = c & 63;
            int rb  = ms * 16 + ((lane >> 4) << 2);
            if (mat == 0) {                   // Q: plain [b][s][64]
                #pragma unroll
                for (int r = 0; r < 4; r++) {
                    float v = acc[ms][ns][r];
                    size_t o = (size_t)(m0 + rb + r) * DHEAD + dk;
                    unsigned short hh = f2bf(v);
                    QH[o] = hh; QL[o] = f2bf(v - bf2f(hh));
                }
            } else if (mat == 1) {            // K: tile-blocked swizzled (rows=kv)
                size_t tb = (size_t)(b * 64 + tile) * 4096;
                #pragma unroll
                for (int r = 0; r < 4; r++) {
                    float v = acc[ms][ns][r];
                    int row = rb + r;
                    size_t o = tb + row * 64 + (dk ^ ((row & 7) << 3));
                    unsigned short hh = f2bf(v);
                    KHs[o] = hh; KLs[o] = f2bf(v - bf2f(hh));
                }
            } else {                          // V: tile-blocked swizzled (rows=dk)
                ushort4v h, l;
                #pragma unroll
                for (int r = 0; r < 4; r++) {
                    float v = acc[ms][ns][r];
                    unsigned short hh = f2bf(v);
                    h[r] = hh; l[r] = f2bf(v - bf2f(hh));
                }
                size_t tb = (size_t)(b * 64 + tile) * 4096;
                size_t o  = tb + dk * 64 + (rb ^ ((dk & 7) << 3)); // rb 4-aligned: contiguous
                *(ushort4v*)(VHs + o) = h;
                *(ushort4v*)(VLs + o) = l;
            }
        }
    }
}

// ---------------------------------------------------------------- kernel 2 --
// Flash chunk: grid 8*160; chunk = 16 kv tiles. 32x32x16 MFMA.
// C/D layout: col=lane&31, row=(r&3)+8*(r>>2)+4*(lane>>5).
__global__ __launch_bounds__(128, 2)
void attn_split_kernel(const unsigned short* __restrict__ QH, const unsigned short* __restrict__ QL,
                       const unsigned short* __restrict__ KHs, const unsigned short* __restrict__ KLs,
                       const unsigned short* __restrict__ VHs, const unsigned short* __restrict__ VLs,
                       float* __restrict__ OP, float* __restrict__ ML,
                       float* __restrict__ out)
{
    __shared__ unsigned char sm[49152];
    constexpr int KHo = 0, KLo = 8192, VHo = 16384, VLo = 24576,
                  PHo = 32768, PLo = 40960;    // P: +w*4096, wave-private
    const int tid  = threadIdx.x;
    const int lane = tid & 63;
    const int w    = tid >> 6;
    const int b    = blockIdx.x & 7;           // low bits -> XCD-local batch KV
    const int c    = 159 - (blockIdx.x >> 3);  // big chunks dispatched first
    // decode chunk id c -> (qb, ch): qb group g has g+1 chunks each
    int g, st;
    if      (c < 16) { g = 0; st = 0;  }
    else if (c < 48) { g = 1; st = 16; }
    else if (c < 96) { g = 2; st = 48; }
    else             { g = 3; st = 96; }
    const int i2 = c - st;
    const int qb = g * 16 + i2 / (g + 1);
    const int ch = i2 - (i2 / (g + 1)) * (g + 1);
    const int t0 = ch * 16;
    const int tend = min(t0 + 16, qb + 1);
    const int q0 = qb * 64;

    // Q fragments straight from global (no LDS round-trip)
    short8 qh[4], ql[4];
    {
        const size_t qrow = (size_t)(b * SEQ + q0 + w * 32 + (lane & 31)) * DHEAD;
        #pragma unroll
        for (int ks = 0; ks < 4; ks++) {
            int off = ks * 16 + ((lane >> 5) << 3);
            qh[ks] = *(const short8*)(QH + qrow + off);
            ql[ks] = *(const short8*)(QL + qrow + off);
        }
    }

    f32x16 oacc[2];
    float m_r[16], l_r[16];
    #pragma unroll
    for (int r = 0; r < 16; r++) { m_r[r] = NEG_BIG; l_r[r] = 0.f; oacc[0][r] = 0.f; oacc[1][r] = 0.f; }

    for (int t = t0; t < tend; ++t) {
        __syncthreads();                       // prev iter LDS reads done
        {
            const size_t tb = (size_t)(b * 64 + t) * 4096;
            #pragma unroll
            for (int i = 0; i < 4; i++) {
                int j  = w * 4 + i;
                int go = j * 512 + lane * 8;   // ushorts
                int lo = j * 1024;             // bytes
                gload16(KHs + tb + go, sm + KHo + lo);
                gload16(KLs + tb + go, sm + KLo + lo);
                gload16(VHs + tb + go, sm + VHo + lo);
                gload16(VLs + tb + go, sm + VLo + lo);
            }
        }
        __syncthreads();                       // barrier drains vmcnt(0)

        // ---- S = Q K^T  (wave: 32 q-rows x 64 kv) ----
        f32x16 sacc[2];
        #pragma unroll
        for (int r = 0; r < 16; r++) { sacc[0][r] = 0.f; sacc[1][r] = 0.f; }
        #pragma unroll
        for (int ks = 0; ks < 4; ks++) {
            #pragma unroll
            for (int sub = 0; sub < 2; sub++) {
                int row = sub * 32 + (lane & 31);
                int off = ks * 32 + ((lane >> 5) << 4);
                short8 kh = *(const short8*)(sm + KHo + swz(row, off));
                short8 kl = *(const short8*)(sm + KLo + swz(row, off));
                sacc[sub] = __builtin_amdgcn_mfma_f32_32x32x16_bf16(qh[ks], kh, sacc[sub], 0, 0, 0);
                sacc[sub] = __builtin_amdgcn_mfma_f32_32x32x16_bf16(qh[ks], kl, sacc[sub], 0, 0, 0);
                sacc[sub] = __builtin_amdgcn_mfma_f32_32x32x16_bf16(ql[ks], kh, sacc[sub], 0, 0, 0);
            }
        }

        // ---- online softmax (fp32) ----
        const bool diag = (t == qb);
        #pragma unroll
        for (int r = 0; r < 16; r++) {
            float s0v = sacc[0][r] * SM_SCALE;
            float s1v = sacc[1][r] * SM_SCALE;
            if (diag) {
                int qi = w * 32 + (r & 3) + ((r >> 2) << 3) + ((lane >> 5) << 2);
                int ci = lane & 31;
                if (ci > qi)      s0v = NEG_BIG;
                if (32 + ci > qi) s1v = NEG_BIG;
            }
            float v = fmaxf(s0v, s1v);
            v = fmaxf(v, __shfl_xor(v, 1, 64));
            v = fmaxf(v, __shfl_xor(v, 2, 64));
            v = fmaxf(v, __shfl_xor(v, 4, 64));
            v = fmaxf(v, __shfl_xor(v, 8, 64));
            v = fmaxf(v, __shfl_xor(v, 16, 64));
            float mn = fmaxf(m_r[r], v);
            float al = __builtin_amdgcn_exp2f((m_r[r] - mn) * LOG2E);
            m_r[r] = mn;
            float p0 = __builtin_amdgcn_exp2f((s0v - mn) * LOG2E);
            float p1 = __builtin_amdgcn_exp2f((s1v - mn) * LOG2E);
            sacc[0][r] = p0; sacc[1][r] = p1;
            float rs = p0 + p1;
            rs += __shfl_xor(rs, 1, 64);
            rs += __shfl_xor(rs, 2, 64);
            rs += __shfl_xor(rs, 4, 64);
            rs += __shfl_xor(rs, 8, 64);
            rs += __shfl_xor(rs, 16, 64);
            l_r[r] = l_r[r] * al + rs;
            oacc[0][r] *= al;
            oacc[1][r] *= al;
        }

        // ---- P -> wave-private LDS (hi/lo) ----
        #pragma unroll
        for (int sub = 0; sub < 2; sub++) {
            #pragma unroll
            for (int r = 0; r < 16; r++) {
                int qr  = (r & 3) + ((r >> 2) << 3) + ((lane >> 5) << 2);
                int col = sub * 32 + (lane & 31);
                int ba  = swz(qr, col * 2);
                float p = sacc[sub][r];
                unsigned short hh = f2bf(p);
                *(unsigned short*)(sm + PHo + w * 4096 + ba) = hh;
                *(unsigned short*)(sm + PLo + w * 4096 + ba) = f2bf(p - bf2f(hh));
            }
        }

        // ---- O += P V ----
        #pragma unroll
        for (int ks = 0; ks < 4; ks++) {
            int prow = lane & 31;
            int poff = ks * 32 + ((lane >> 5) << 4);
            short8 pah = *(const short8*)(sm + PHo + w * 4096 + swz(prow, poff));
            short8 pal = *(const short8*)(sm + PLo + w * 4096 + swz(prow, poff));
            #pragma unroll
            for (int dsub = 0; dsub < 2; dsub++) {
                int vrow = dsub * 32 + (lane & 31);
                short8 vh = *(const short8*)(sm + VHo + swz(vrow, poff));
                short8 vl = *(const short8*)(sm + VLo + swz(vrow, poff));
                oacc[dsub] = __builtin_amdgcn_mfma_f32_32x32x16_bf16(pah, vh, oacc[dsub], 0, 0, 0);
                oacc[dsub] = __builtin_amdgcn_mfma_f32_32x32x16_bf16(pah, vl, oacc[dsub], 0, 0, 0);
                oacc[dsub] = __builtin_amdgcn_mfma_f32_32x32x16_bf16(pal, vh, oacc[dsub], 0, 0, 0);
            }
        }
    }

    // ---- epilogue ----
    if (g == 0) {                              // single chunk: write final output
        #pragma unroll
        for (int dsub = 0; dsub < 2; dsub++) {
            #pragma unroll
            for (int r = 0; r < 16; r++) {
                int qr = (r & 3) + ((r >> 2) << 3) + ((lane >> 5) << 2);
                size_t o = (size_t)(b * SEQ + q0 + w * 32 + qr) * DHEAD + dsub * 32 + (lane & 31);
                out[o] = oacc[dsub][r] / l_r[r];
            }
        }
    } else {                                   // partial: unnormalized O + (m,l)
        const size_t cbase = (size_t)((b * 64 + qb) * 4 + ch);
        #pragma unroll
        for (int dsub = 0; dsub < 2; dsub++) {
            #pragma unroll
            for (int r = 0; r < 16; r++) {
                int qr = (r & 3) + ((r >> 2) << 3) + ((lane >> 5) << 2);
                size_t o = cbase * 4096 + (size_t)(w * 32 + qr) * 64 + dsub * 32 + (lane & 31);
                OP[o] = oacc[dsub][r];
            }
        }
        if ((lane & 31) == 0) {                // lanes 0 and 32 own all 32 rows
            #pragma unroll
            for (int r = 0; r < 16; r++) {
                int qr = (r & 3) + ((r >> 2) << 3) + ((lane >> 5) << 2);
                size_t o = cbase * 128 + (size_t)(w * 32 + qr) * 2;
                ML[o] = m_r[r]; ML[o + 1] = l_r[r];
            }
        }
    }
}

// ---------------------------------------------------------------- kernel 3 --
// Merge chunks for qb >= 16. grid 8*48, 256 thr; thread = (row, col-quad).
__global__ __launch_bounds__(256, 4)
void combine_kernel(const float* __restrict__ OP, const float* __restrict__ ML,
                    float* __restrict__ out)
{
    const int b  = blockIdx.x & 7;
    const int qb = 16 + (blockIdx.x >> 3);
    const int nc = (qb >> 4) + 1;              // 2..4 chunks
    const int r    = threadIdx.x >> 2;         // 0..63
    const int quad = threadIdx.x & 3;          // 16-col quad
    const size_t cbase = (size_t)(b * 64 + qb) * 4;

    float mv[4], lv[4];
    float M = NEG_BIG;
    #pragma unroll
    for (int ch = 0; ch < 4; ch++) if (ch < nc) {
        mv[ch] = ML[(cbase + ch) * 128 + r * 2];
        lv[ch] = ML[(cbase + ch) * 128 + r * 2 + 1];
        M = fmaxf(M, mv[ch]);
    }
    float L = 0.f, sc[4];
    #pragma unroll
    for (int ch = 0; ch < 4; ch++) if (ch < nc) {
        sc[ch] = __builtin_amdgcn_exp2f((mv[ch] - M) * LOG2E);
        L += lv[ch] * sc[ch];
    }
    const float inv = 1.f / L;

    f32x4 acc[4];
    #pragma unroll
    for (int j = 0; j < 4; j++) { acc[j][0] = 0.f; acc[j][1] = 0.f; acc[j][2] = 0.f; acc[j][3] = 0.f; }
    #pragma unroll
    for (int ch = 0; ch < 4; ch++) if (ch < nc) {
        const float* base = OP + (cbase + ch) * 4096 + (size_t)r * 64 + quad * 16;
        #pragma unroll
        for (int j = 0; j < 4; j++) {
            f32x4 vv = *(const f32x4*)(base + j * 4);
            acc[j] += vv * sc[ch];
        }
    }
    float* ob = out + (size_t)(b * SEQ + qb * 64 + r) * 64 + quad * 16;
    #pragma unroll
    for (int j = 0; j < 4; j++) *(f32x4*)(ob + j * 4) = acc[j] * inv;
}

// ------------------------------------------------------------------- launch --
extern "C" void kernel_launch(void* const* d_in, const int* in_sizes, int n_in,
                              void* d_out, int out_size, void* d_ws, size_t ws_size,
                              hipStream_t stream)
{
    const float* x  = (const float*)d_in[0];
    const float* wQ = (const float*)d_in[1];
    const float* wK = (const float*)d_in[2];
    const float* wV = (const float*)d_in[3];
    float* out = (float*)d_out;

    // workspace layout: ushort arrays then float arrays (~58 MB total)
    unsigned short* p   = (unsigned short*)d_ws;
    unsigned short* WHs = p; p += 192 * 1024;
    unsigned short* WLs = p; p += 192 * 1024;
    unsigned short* QHp = p; p += 8 * 4096 * 64;
    unsigned short* QLp = p; p += 8 * 4096 * 64;
    unsigned short* KHs = p; p += 8 * 4096 * 64;
    unsigned short* KLs = p; p += 8 * 4096 * 64;
    unsigned short* VHs = p; p += 8 * 4096 * 64;
    unsigned short* VLs = p; p += 8 * 4096 * 64;
    float* fp = (float*)p;                      // 16B-aligned (offset 25952256)
    float* OP = fp; fp += (size_t)8 * 64 * 4 * 4096;   // 33.5 MB partial O
    float* ML = fp; fp += (size_t)8 * 64 * 4 * 64 * 2; // 1 MB (m,l)

    splitw_kernel<<<dim3(192), dim3(256), 0, stream>>>(wQ, wK, wV, WHs, WLs);
    proj_kernel<<<dim3(512), dim3(256), 0, stream>>>(x, WHs, WLs, QHp, QLp, KHs, KLs, VHs, VLs);
    attn_split_kernel<<<dim3(1280), dim3(128), 0, stream>>>(QHp, QLp, KHs, KLs, VHs, VLs, OP, ML, out);
    combine_kernel<<<dim3(384), dim3(256), 0, stream>>>(OP, ML, out);
}

// Round 3
// 320.851 us; speedup vs baseline: 2.2914x; 1.3904x over previous
//
#include <hip/hip_runtime.h>
#include <hip/hip_bf16.h>

// ============================================================================
// AttentionHead (B=8,S=4096,D=1024,DK=64), fp32 in/out — MI355X gfx950
// R3: swapped-QK^T in-register softmax (T12), no P LDS, 4-wave/QB=128 attn
//     blocks, reg-direct W in proj (no vmem drain at barriers), split-K flash.
// Precision: split-bf16 (hi+lo) x 3-product MFMA => ~fp32 accuracy.
// K0 splitw : W -> bf16 hi/lo, k-chunked [kb][192][8] layout
// K1 proj   : Q (pre-scaled by dm^-.5*log2e), K/V -> attn-tile swizzled KV
// K2 attn   : flash chunk, QB=128, KVB=64, 4 waves, 32x32x16 bf16 MFMA,
//             S^T in regs (lane = q col), scalar m/l per lane
// K3 combine: merge partial (O,m,l) chunks (exp2 domain)
// LDS KV tiles: [64 rows][64] bf16, pitch 128B, XOR swizzle ^((row&7)<<4).
// ============================================================================

typedef __attribute__((ext_vector_type(8)))  short   short8;
typedef __attribute__((ext_vector_type(4)))  float   f32x4;
typedef __attribute__((ext_vector_type(16))) float   f32x16;
typedef __attribute__((ext_vector_type(4)))  unsigned short ushort4v;

#define DEV static __device__ __forceinline__

constexpr int SEQ    = 4096;
constexpr int DMODEL = 1024;
constexpr int DHEAD  = 64;
// fold d_model^-0.5 AND log2(e) into Q so attn uses exp2 directly
constexpr float QSCALE = 0.03125f * 1.44269504088896340736f;
constexpr float MASK_S = -30000.f;   // masked score (log2 domain), finite
constexpr float M_INIT = -10000.f;   // running-max init; MASK_S - M_INIT << 0

DEV unsigned short f2bf(float x) {           // fp32 -> bf16 RNE
    union { float f; unsigned u; } v; v.f = x;
    unsigned r = v.u + 0x7fffu + ((v.u >> 16) & 1u);
    return (unsigned short)(r >> 16);
}
DEV float bf2f(unsigned short h) {
    union { unsigned u; float f; } v; v.u = ((unsigned)h) << 16;
    return v.f;
}
DEV float asf(unsigned u) { union { unsigned u; float f; } v; v.u = u; return v.f; }
// byte address inside a [rows][64]bf16 tile (pitch 128B) with XOR swizzle
DEV int swz(int row, int off) { return row * 128 + (off ^ ((row & 7) << 4)); }

DEV unsigned cvtpk(float lo, float hi) {     // pack 2 fp32 -> 2 bf16 (lo|hi<<16)
    unsigned r;
    asm("v_cvt_pk_bf16_f32 %0, %1, %2" : "=v"(r) : "v"(lo), "v"(hi));
    return r;
}
DEV short8 mk8(unsigned a, unsigned b, unsigned c, unsigned d) {
    union { unsigned u[4]; short8 s; } x;
    x.u[0] = a; x.u[1] = b; x.u[2] = c; x.u[3] = d; return x.s;
}

// async 16B global -> LDS (linear dest; source layouts are pre-swizzled)
DEV void gload16(const unsigned short* g, unsigned char* l) {
    __builtin_amdgcn_global_load_lds(
        (const __attribute__((address_space(1))) unsigned int*)g,
        (__attribute__((address_space(3))) unsigned int*)l, 16, 0, 0);
}

// ---------------------------------------------------------------- kernel 0 --
// W -> bf16 hi/lo, layout [kb=k/8][row 0..191][8]  (coalesced frag reads)
__global__ void splitw_kernel(const float* __restrict__ wQ,
                              const float* __restrict__ wK,
                              const float* __restrict__ wV,
                              unsigned short* __restrict__ WHp,
                              unsigned short* __restrict__ WLp)
{
    int t   = blockIdx.x * 256 + threadIdx.x;  // 49152 float4 chunks, exact
    int fl  = t * 4;
    int row = fl >> 10;                        // 0..191 (Q,K,V stacked)
    int k   = fl & 1023;
    const float* src = (row < 64) ? wQ : (row < 128 ? wK : wV);
    float4 v = *(const float4*)(src + (row & 63) * 1024 + k);
    float vv[4] = {v.x, v.y, v.z, v.w};
    ushort4v h, l;
    #pragma unroll
    for (int j = 0; j < 4; j++) {
        unsigned short hh = f2bf(vv[j]);
        h[j] = hh;
        l[j] = f2bf(vv[j] - bf2f(hh));
    }
    size_t u = (size_t)(k >> 3) * 1536 + row * 8 + (k & 7);
    *(ushort4v*)(WHp + u) = h;
    *(ushort4v*)(WLp + u) = l;
}

// ---------------------------------------------------------------- kernel 1 --
// M=64 rows/block, 512 blocks, 4 waves; wave w owns cols [48w,48w+48).
// K-step 64, 16 iters. W frags reg-direct from global; x dbuf in LDS.
__global__ __launch_bounds__(256, 3)
void proj_kernel(const float* __restrict__ x,
                 const unsigned short* __restrict__ WHp,
                 const unsigned short* __restrict__ WLp,
                 unsigned short* __restrict__ QH, unsigned short* __restrict__ QL,
                 unsigned short* __restrict__ KV)
{
    __shared__ unsigned char sm[32768];        // X dbuf: [cur][hi 8KB | lo 8KB]
    const int tid  = threadIdx.x;
    const int lane = tid & 63;
    const int w    = tid >> 6;
    const int m0   = blockIdx.x * 64;          // global row base (b*4096+s0)
    const int b    = m0 >> 12;
    const int s0   = m0 & 4095;
    const int tile = s0 >> 6;

    f32x4 acc[4][3];
    #pragma unroll
    for (int i = 0; i < 4; i++)
        #pragma unroll
        for (int j = 0; j < 3; j++)
            #pragma unroll
            for (int r = 0; r < 4; r++) acc[i][j][r] = 0.f;

    // prologue: stage x tile for kt=0 into buf0
    {
        #pragma unroll
        for (int i = 0; i < 4; i++) {
            int c = tid + i * 256;
            int row = c >> 4, c16 = c & 15;
            float4 v = *(const float4*)(x + (size_t)(m0 + row) * DMODEL + c16 * 4);
            float vv[4] = {v.x, v.y, v.z, v.w};
            ushort4v hh, ll;
            #pragma unroll
            for (int j = 0; j < 4; j++) {
                unsigned short h1 = f2bf(vv[j]);
                hh[j] = h1; ll[j] = f2bf(vv[j] - bf2f(h1));
            }
            int ba = swz(row, c16 * 8);
            *(ushort4v*)(sm + ba) = hh;
            *(ushort4v*)(sm + 8192 + ba) = ll;
        }
        __syncthreads();
    }

    for (int kt = 0; kt < 16; ++kt) {
        const int cur = kt & 1;
        unsigned char* xh = sm + cur * 16384;
        unsigned char* xl = xh + 8192;
        const bool last = (kt == 15);
        // W fragments for this kt (reg-direct, L2/L3-resident)
        short8 wfh[2][3], wfl[2][3];
        #pragma unroll
        for (int ks = 0; ks < 2; ks++)
            #pragma unroll
            for (int ns = 0; ns < 3; ns++) {
                int rown = w * 48 + ns * 16 + (lane & 15);
                size_t kb = (size_t)kt * 8 + ks * 4 + (lane >> 4);
                wfh[ks][ns] = *(const short8*)(WHp + kb * 1536 + rown * 8);
                wfl[ks][ns] = *(const short8*)(WLp + kb * 1536 + rown * 8);
            }
        // x loads for kt+1 (consumed after MFMA)
        float4 xn[4];
        if (!last) {
            #pragma unroll
            for (int i = 0; i < 4; i++) {
                int c = tid + i * 256;
                int row = c >> 4, c16 = c & 15;
                xn[i] = *(const float4*)(x + (size_t)(m0 + row) * DMODEL + (kt + 1) * 64 + c16 * 4);
            }
        }
        // MFMA over current buffers
        #pragma unroll
        for (int ks = 0; ks < 2; ks++) {
            short8 ah[4], al[4];
            #pragma unroll
            for (int ms = 0; ms < 4; ms++) {
                int rowm = ms * 16 + (lane & 15);
                int off  = ks * 64 + ((lane >> 4) << 4);
                ah[ms] = *(const short8*)(xh + swz(rowm, off));
                al[ms] = *(const short8*)(xl + swz(rowm, off));
            }
            #pragma unroll
            for (int ns = 0; ns < 3; ns++) {
                #pragma unroll
                for (int ms = 0; ms < 4; ms++) {
                    acc[ms][ns] = __builtin_amdgcn_mfma_f32_16x16x32_bf16(ah[ms], wfh[ks][ns], acc[ms][ns], 0, 0, 0);
                    acc[ms][ns] = __builtin_amdgcn_mfma_f32_16x16x32_bf16(ah[ms], wfl[ks][ns], acc[ms][ns], 0, 0, 0);
                    acc[ms][ns] = __builtin_amdgcn_mfma_f32_16x16x32_bf16(al[ms], wfh[ks][ns], acc[ms][ns], 0, 0, 0);
                }
            }
        }
        // split next x tile into the other buffer
        if (!last) {
            unsigned char* nh = sm + (cur ^ 1) * 16384;
            unsigned char* nl = nh + 8192;
            #pragma unroll
            for (int i = 0; i < 4; i++) {
                int c = tid + i * 256;
                int row = c >> 4, c16 = c & 15;
                float vv[4] = {xn[i].x, xn[i].y, xn[i].z, xn[i].w};
                ushort4v hh, ll;
                #pragma unroll
                for (int j = 0; j < 4; j++) {
                    unsigned short h1 = f2bf(vv[j]);
                    hh[j] = h1; ll[j] = f2bf(vv[j] - bf2f(h1));
                }
                int ba = swz(row, c16 * 8);
                *(ushort4v*)(nh + ba) = hh;
                *(ushort4v*)(nl + ba) = ll;
            }
        }
        __syncthreads();
    }

    // epilogue: C/D 16x16 layout: col = lane&15, row = (lane>>4)*4 + r
    #pragma unroll
    for (int ms = 0; ms < 4; ms++) {
        #pragma unroll
        for (int ns = 0; ns < 3; ns++) {
            int c   = w * 48 + ns * 16 + (lane & 15);
            int mat = c >> 6;                 // 0=Q 1=K 2=V (uniform per w,ns)
            int dk  = c & 63;
            int rb  = ms * 16 + ((lane >> 4) << 2);
            const size_t tb = (size_t)(b * 64 + tile) * 16384;
            if (mat == 0) {                   // Q: plain [b][s][64], pre-scaled
                #pragma unroll
                for (int r = 0; r < 4; r++) {
                    float v = acc[ms][ns][r] * QSCALE;
                    size_t o = (size_t)(m0 + rb + r) * DHEAD + dk;
                    unsigned short hh = f2bf(v);
                    QH[o] = hh; QL[o] = f2bf(v - bf2f(hh));
                }
            } else if (mat == 1) {            // K: KV parts 0(hi),1(lo), rows=kv
                #pragma unroll
                for (int r = 0; r < 4; r++) {
                    float v = acc[ms][ns][r];
                    int row = rb + r;
                    size_t o = tb + row * 64 + (dk ^ ((row & 7) << 3));
                    unsigned short hh = f2bf(v);
                    KV[o] = hh; KV[o + 4096] = f2bf(v - bf2f(hh));
                }
            } else {                          // V: parts 2,3, rows=dk (V^T)
                ushort4v h, l;
                #pragma unroll
                for (int r = 0; r < 4; r++) {
                    float v = acc[ms][ns][r];
                    unsigned short hh = f2bf(v);
                    h[r] = hh; l[r] = f2bf(v - bf2f(hh));
                }
                size_t o = tb + 8192 + dk * 64 + (rb ^ ((dk & 7) << 3));
                *(ushort4v*)(KV + o) = h;
                *(ushort4v*)(KV + o + 4096) = l;
            }
        }
    }
}

// ---------------------------------------------------------------- kernel 2 --
// Flash chunk: QB=128, 4 waves (wave w = q rows [q0+32w, +32)), KVB=64.
// Swapped QK^T: sacc = S^T (col=lane&31 = q, rows = kv). Scalar m/l per lane.
__global__ __launch_bounds__(256, 3)
void attn_kernel(const unsigned short* __restrict__ QH, const unsigned short* __restrict__ QL,
                 const unsigned short* __restrict__ KV,
                 float* __restrict__ OP, float* __restrict__ ML,
                 float* __restrict__ out)
{
    __shared__ unsigned char sm[32768];        // [KH 8K][KL 8K][VH 8K][VL 8K]
    const int tid  = threadIdx.x;
    const int lane = tid & 63;
    const int hi   = lane >> 5;
    const int w    = tid >> 6;
    const int b    = blockIdx.x & 7;           // batch == XCD slot: KV L2-local
    const int c    = 79 - (int)(blockIdx.x >> 3);  // big chunks first
    int qb, ch;
    if      (c < 8)  { qb = c;                ch = 0; }
    else if (c < 24) { qb = 8 + ((c - 8) >> 1);  ch = (c - 8) & 1; }
    else if (c < 48) { qb = 16 + (c - 24) / 3;   ch = (c - 24) % 3; }
    else             { qb = 24 + ((c - 48) >> 2); ch = (c - 48) & 3; }
    const int nt   = 2 * qb + 2;
    const int t0   = ch * 16;
    const int tend = min(t0 + 16, nt);
    const int nc   = (qb < 8) ? 1 : ((qb < 16) ? 2 : ((qb < 24) ? 3 : 4));
    const int q0   = qb * 128;
    const int qABase = q0 + w * 32;            // wave's lowest q row
    const int qi     = qABase + (lane & 31);   // this lane's q row

    // Q fragments (B-operand: col=q, k=hi*8+j), straight from global
    short8 qh[4], ql[4];
    {
        const size_t qrow = (size_t)(b * SEQ + qi) * DHEAD;
        #pragma unroll
        for (int ks = 0; ks < 4; ks++) {
            int off = ks * 16 + hi * 8;
            qh[ks] = *(const short8*)(QH + qrow + off);
            ql[ks] = *(const short8*)(QL + qrow + off);
        }
    }

    f32x16 oacc[2];                            // O^T: col=q, rows=d (+32*dsub)
    #pragma unroll
    for (int r = 0; r < 16; r++) { oacc[0][r] = 0.f; oacc[1][r] = 0.f; }
    float m_s = M_INIT, l_s = 0.f;

    for (int t = t0; t < tend; ++t) {
        const int kv0 = t * 64;
        __syncthreads();                       // prev tile LDS reads done
        {
            const unsigned short* src = KV + (size_t)(b * 64 + t) * 16384 + w * 4096 + lane * 8;
            unsigned char* dst = sm + w * 8192;
            #pragma unroll
            for (int i = 0; i < 8; i++)
                gload16(src + i * 512, dst + i * 1024);
        }
        __syncthreads();                       // drains vmcnt(0)

        if (kv0 > qABase + 31) continue;       // wave fully above diagonal

        // ---- S^T = K Q^T  (A=K rows=kv, B=Q cols=q) ----
        f32x16 sacc[2];
        #pragma unroll
        for (int r = 0; r < 16; r++) { sacc[0][r] = 0.f; sacc[1][r] = 0.f; }
        #pragma unroll
        for (int sub = 0; sub < 2; sub++) {
            int row = sub * 32 + (lane & 31);
            #pragma unroll
            for (int ks = 0; ks < 4; ks++) {
                int off = ks * 32 + hi * 16;
                short8 kh = *(const short8*)(sm + swz(row, off));
                short8 kl = *(const short8*)(sm + 8192 + swz(row, off));
                sacc[sub] = __builtin_amdgcn_mfma_f32_32x32x16_bf16(kh, qh[ks], sacc[sub], 0, 0, 0);
                sacc[sub] = __builtin_amdgcn_mfma_f32_32x32x16_bf16(kh, ql[ks], sacc[sub], 0, 0, 0);
                sacc[sub] = __builtin_amdgcn_mfma_f32_32x32x16_bf16(kl, qh[ks], sacc[sub], 0, 0, 0);
            }
        }

        // ---- causal mask (finite sentinel) ----
        if (kv0 + 63 > qABase) {
            #pragma unroll
            for (int sub = 0; sub < 2; sub++)
                #pragma unroll
                for (int r = 0; r < 16; r++) {
                    int kvg = kv0 + sub * 32 + (r & 3) + 8 * (r >> 2) + 4 * hi;
                    if (kvg > qi) sacc[sub][r] = MASK_S;
                }
        }

        // ---- in-register online softmax (per-lane scalars) ----
        float vm = sacc[0][0];
        #pragma unroll
        for (int sub = 0; sub < 2; sub++)
            #pragma unroll
            for (int r = 0; r < 16; r++) vm = fmaxf(vm, sacc[sub][r]);
        vm = fmaxf(vm, __shfl_xor(vm, 32));
        const float mnew = fmaxf(m_s, vm);
        const float alff = __builtin_amdgcn_exp2f(m_s - mnew);
        m_s = mnew;
        float rs = 0.f;
        #pragma unroll
        for (int sub = 0; sub < 2; sub++)
            #pragma unroll
            for (int r = 0; r < 16; r++) {
                float p = __builtin_amdgcn_exp2f(sacc[sub][r] - mnew);
                sacc[sub][r] = p;
                rs += p;
            }
        rs += __shfl_xor(rs, 32);
        l_s = l_s * alff + rs;
        #pragma unroll
        for (int r = 0; r < 16; r++) { oacc[0][r] *= alff; oacc[1][r] *= alff; }

        // ---- P -> bf16 hi/lo frags + PV (O^T += V^T P^T) ----
        #pragma unroll
        for (int ks = 0; ks < 4; ks++) {
            const int sub = ks >> 1, rb = (ks & 1) * 8;
            float v0 = sacc[sub][rb + 0], v1 = sacc[sub][rb + 1];
            float v2 = sacc[sub][rb + 2], v3 = sacc[sub][rb + 3];
            float v4 = sacc[sub][rb + 4], v5 = sacc[sub][rb + 5];
            float v6 = sacc[sub][rb + 6], v7 = sacc[sub][rb + 7];
            unsigned Ah0 = cvtpk(v0, v1), Ah1 = cvtpk(v2, v3);
            unsigned Bh0 = cvtpk(v4, v5), Bh1 = cvtpk(v6, v7);
            float l0 = v0 - asf(Ah0 << 16), l1 = v1 - asf(Ah0 & 0xffff0000u);
            float l2 = v2 - asf(Ah1 << 16), l3 = v3 - asf(Ah1 & 0xffff0000u);
            float l4 = v4 - asf(Bh0 << 16), l5 = v5 - asf(Bh0 & 0xffff0000u);
            float l6 = v6 - asf(Bh1 << 16), l7 = v7 - asf(Bh1 & 0xffff0000u);
            unsigned Al0 = cvtpk(l0, l1), Al1 = cvtpk(l2, l3);
            unsigned Bl0 = cvtpk(l4, l5), Bl1 = cvtpk(l6, l7);
            // exchange: hi=0 sends B(kv8-11), gets partner A(kv4-7); hi=1 opp.
            unsigned eh0 = __shfl_xor(hi ? Ah0 : Bh0, 32);
            unsigned eh1 = __shfl_xor(hi ? Ah1 : Bh1, 32);
            unsigned el0 = __shfl_xor(hi ? Al0 : Bl0, 32);
            unsigned el1 = __shfl_xor(hi ? Al1 : Bl1, 32);
            short8 PH = hi ? mk8(eh0, eh1, Bh0, Bh1) : mk8(Ah0, Ah1, eh0, eh1);
            short8 PL = hi ? mk8(el0, el1, Bl0, Bl1) : mk8(Al0, Al1, el0, el1);
            const int off = ks * 32 + hi * 16;
            #pragma unroll
            for (int dsub = 0; dsub < 2; dsub++) {
                int vrow = dsub * 32 + (lane & 31);
                short8 vh = *(const short8*)(sm + 16384 + swz(vrow, off));
                short8 vl = *(const short8*)(sm + 24576 + swz(vrow, off));
                oacc[dsub] = __builtin_amdgcn_mfma_f32_32x32x16_bf16(vh, PH, oacc[dsub], 0, 0, 0);
                oacc[dsub] = __builtin_amdgcn_mfma_f32_32x32x16_bf16(vh, PL, oacc[dsub], 0, 0, 0);
                oacc[dsub] = __builtin_amdgcn_mfma_f32_32x32x16_bf16(vl, PH, oacc[dsub], 0, 0, 0);
            }
        }
    }

    // ---- epilogue: O^T cols=q, rows d = dsub*32 + 8*rg + 4*hi + (r&3) ----
    if (nc == 1) {
        const float inv = 1.f / l_s;
        float* orow = out + (size_t)(b * SEQ + qi) * DHEAD;
        #pragma unroll
        for (int dsub = 0; dsub < 2; dsub++)
            #pragma unroll
            for (int rg = 0; rg < 4; rg++) {
                f32x4 v;
                #pragma unroll
                for (int j = 0; j < 4; j++) v[j] = oacc[dsub][rg * 4 + j] * inv;
                *(f32x4*)(orow + dsub * 32 + rg * 8 + hi * 4) = v;
            }
    } else {
        const size_t cbase = (size_t)((b * 32 + qb) * 4 + ch);
        float* orow = OP + cbase * 8192 + (size_t)(w * 32 + (lane & 31)) * 64;
        #pragma unroll
        for (int dsub = 0; dsub < 2; dsub++)
            #pragma unroll
            for (int rg = 0; rg < 4; rg++) {
                f32x4 v;
                #pragma unroll
                for (int j = 0; j < 4; j++) v[j] = oacc[dsub][rg * 4 + j];
                *(f32x4*)(orow + dsub * 32 + rg * 8 + hi * 4) = v;
            }
        if (hi == 0) {
            size_t o = cbase * 256 + (size_t)(w * 32 + lane) * 2;
            ML[o] = m_s; ML[o + 1] = l_s;
        }
    }
}

// ---------------------------------------------------------------- kernel 3 --
// Merge chunks for qb >= 8 (2..4 chunks). grid 8*24, 256 thr. exp2 domain.
__global__ __launch_bounds__(256, 4)
void combine_kernel(const float* __restrict__ OP, const float* __restrict__ ML,
                    float* __restrict__ out)
{
    const int b   = blockIdx.x & 7;
    const int qb  = 8 + (int)(blockIdx.x >> 3);
    const int nc  = (qb < 16) ? 2 : ((qb < 24) ? 3 : 4);
    const int qlo = threadIdx.x >> 1;          // 0..127
    const int d0  = (threadIdx.x & 1) * 32;
    const size_t cbase = (size_t)(b * 32 + qb) * 4;

    float mv[4], lv[4];
    float M = MASK_S;
    #pragma unroll
    for (int ch = 0; ch < 4; ch++) if (ch < nc) {
        mv[ch] = ML[(cbase + ch) * 256 + qlo * 2];
        lv[ch] = ML[(cbase + ch) * 256 + qlo * 2 + 1];
        M = fmaxf(M, mv[ch]);
    }
    float L = 0.f, sc[4];
    #pragma unroll
    for (int ch = 0; ch < 4; ch++) if (ch < nc) {
        sc[ch] = __builtin_amdgcn_exp2f(mv[ch] - M);
        L += lv[ch] * sc[ch];
    }
    const float inv = 1.f / L;

    f32x4 acc[8];
    #pragma unroll
    for (int j = 0; j < 8; j++) { acc[j][0] = 0.f; acc[j][1] = 0.f; acc[j][2] = 0.f; acc[j][3] = 0.f; }
    #pragma unroll
    for (int ch = 0; ch < 4; ch++) if (ch < nc) {
        const float* bp = OP + (cbase + ch) * 8192 + (size_t)qlo * 64 + d0;
        #pragma unroll
        for (int j = 0; j < 8; j++) acc[j] += *(const f32x4*)(bp + j * 4) * sc[ch];
    }
    float* ob = out + (size_t)(b * SEQ + qb * 128 + qlo) * 64 + d0;
    #pragma unroll
    for (int j = 0; j < 8; j++) *(f32x4*)(ob + j * 4) = acc[j] * inv;
}

// ------------------------------------------------------------------- launch --
extern "C" void kernel_launch(void* const* d_in, const int* in_sizes, int n_in,
                              void* d_out, int out_size, void* d_ws, size_t ws_size,
                              hipStream_t stream)
{
    const float* x  = (const float*)d_in[0];
    const float* wQ = (const float*)d_in[1];
    const float* wK = (const float*)d_in[2];
    const float* wV = (const float*)d_in[3];
    float* out = (float*)d_out;

    // workspace: W 0.75MB + Q 8.4MB + KV 16.8MB + OP 33.5MB + ML 1MB ~= 60.5MB
    unsigned short* p   = (unsigned short*)d_ws;
    unsigned short* WHp = p; p += 192 * 1024;
    unsigned short* WLp = p; p += 192 * 1024;
    unsigned short* QHp = p; p += 8 * 4096 * 64;
    unsigned short* QLp = p; p += 8 * 4096 * 64;
    unsigned short* KVp = p; p += (size_t)8 * 64 * 16384;
    float* fp = (float*)p;
    float* OP = fp; fp += (size_t)8 * 32 * 4 * 8192;   // partial O
    float* ML = fp; fp += (size_t)8 * 32 * 4 * 256;    // (m,l)

    splitw_kernel<<<dim3(192), dim3(256), 0, stream>>>(wQ, wK, wV, WHp, WLp);
    proj_kernel<<<dim3(512), dim3(256), 0, stream>>>(x, WHp, WLp, QHp, QLp, KVp);
    attn_kernel<<<dim3(640), dim3(256), 0, stream>>>(QHp, QLp, KVp, OP, ML, out);
    combine_kernel<<<dim3(192), dim3(256), 0, stream>>>(OP, ML, out);
}

// Round 4
// 320.347 us; speedup vs baseline: 2.2950x; 1.0016x over previous
//
#include <hip/hip_runtime.h>
#include <hip/hip_bf16.h>

// ============================================================================
// AttentionHead (B=8,S=4096,D=1024,DK=64), fp32 in/out — MI355X gfx950
// R4: proj M=32 tiles (1024 blocks, 4/CU) ; attn LDS double-buffer with
//     issue-early staging (stage t+1 before compute of t). Math unchanged.
// Precision: split-bf16 (hi+lo) x 3-product MFMA => ~fp32 accuracy.
// K0 splitw : W -> bf16 hi/lo, k-chunked [kb][192][8] layout
// K1 proj   : Q (pre-scaled by dm^-.5*log2e), K/V -> attn-tile swizzled KV
// K2 attn   : flash chunk, QB=128, KVB=64, 4 waves, 32x32x16 bf16 MFMA,
//             S^T in regs (lane = q col), scalar m/l per lane, KV dbuf
// K3 combine: merge partial (O,m,l) chunks (exp2 domain)
// LDS KV tiles: [64 rows][64] bf16, pitch 128B, XOR swizzle ^((row&7)<<4).
// ============================================================================

typedef __attribute__((ext_vector_type(8)))  short   short8;
typedef __attribute__((ext_vector_type(4)))  float   f32x4;
typedef __attribute__((ext_vector_type(16))) float   f32x16;
typedef __attribute__((ext_vector_type(4)))  unsigned short ushort4v;

#define DEV static __device__ __forceinline__

constexpr int SEQ    = 4096;
constexpr int DMODEL = 1024;
constexpr int DHEAD  = 64;
// fold d_model^-0.5 AND log2(e) into Q so attn uses exp2 directly
constexpr float QSCALE = 0.03125f * 1.44269504088896340736f;
constexpr float MASK_S = -30000.f;   // masked score (log2 domain), finite
constexpr float M_INIT = -10000.f;   // running-max init; MASK_S - M_INIT << 0

DEV unsigned short f2bf(float x) {           // fp32 -> bf16 RNE
    union { float f; unsigned u; } v; v.f = x;
    unsigned r = v.u + 0x7fffu + ((v.u >> 16) & 1u);
    return (unsigned short)(r >> 16);
}
DEV float bf2f(unsigned short h) {
    union { unsigned u; float f; } v; v.u = ((unsigned)h) << 16;
    return v.f;
}
DEV float asf(unsigned u) { union { unsigned u; float f; } v; v.u = u; return v.f; }
// byte address inside a [rows][64]bf16 tile (pitch 128B) with XOR swizzle
DEV int swz(int row, int off) { return row * 128 + (off ^ ((row & 7) << 4)); }

DEV unsigned cvtpk(float lo, float hi) {     // pack 2 fp32 -> 2 bf16 (lo|hi<<16)
    unsigned r;
    asm("v_cvt_pk_bf16_f32 %0, %1, %2" : "=v"(r) : "v"(lo), "v"(hi));
    return r;
}
DEV short8 mk8(unsigned a, unsigned b, unsigned c, unsigned d) {
    union { unsigned u[4]; short8 s; } x;
    x.u[0] = a; x.u[1] = b; x.u[2] = c; x.u[3] = d; return x.s;
}

// async 16B global -> LDS (linear dest; source layouts are pre-swizzled)
DEV void gload16(const unsigned short* g, unsigned char* l) {
    __builtin_amdgcn_global_load_lds(
        (const __attribute__((address_space(1))) unsigned int*)g,
        (__attribute__((address_space(3))) unsigned int*)l, 16, 0, 0);
}

// ---------------------------------------------------------------- kernel 0 --
// W -> bf16 hi/lo, layout [kb=k/8][row 0..191][8]  (coalesced frag reads)
__global__ void splitw_kernel(const float* __restrict__ wQ,
                              const float* __restrict__ wK,
                              const float* __restrict__ wV,
                              unsigned short* __restrict__ WHp,
                              unsigned short* __restrict__ WLp)
{
    int t   = blockIdx.x * 256 + threadIdx.x;  // 49152 float4 chunks, exact
    int fl  = t * 4;
    int row = fl >> 10;                        // 0..191 (Q,K,V stacked)
    int k   = fl & 1023;
    const float* src = (row < 64) ? wQ : (row < 128 ? wK : wV);
    float4 v = *(const float4*)(src + (row & 63) * 1024 + k);
    float vv[4] = {v.x, v.y, v.z, v.w};
    ushort4v h, l;
    #pragma unroll
    for (int j = 0; j < 4; j++) {
        unsigned short hh = f2bf(vv[j]);
        h[j] = hh;
        l[j] = f2bf(vv[j] - bf2f(hh));
    }
    size_t u = (size_t)(k >> 3) * 1536 + row * 8 + (k & 7);
    *(ushort4v*)(WHp + u) = h;
    *(ushort4v*)(WLp + u) = l;
}

// ---------------------------------------------------------------- kernel 1 --
// M=32 rows/block, 1024 blocks (4/CU), 4 waves; wave w owns cols [48w,48w+48).
// K-step 64, 16 iters. W frags reg-direct from global; x dbuf in LDS (16KB).
__global__ __launch_bounds__(256, 4)
void proj_kernel(const float* __restrict__ x,
                 const unsigned short* __restrict__ WHp,
                 const unsigned short* __restrict__ WLp,
                 unsigned short* __restrict__ QH, unsigned short* __restrict__ QL,
                 unsigned short* __restrict__ KV)
{
    __shared__ unsigned char sm[16384];        // dbuf: [cur][hi 4KB | lo 4KB]
    const int tid  = threadIdx.x;
    const int lane = tid & 63;
    const int w    = tid >> 6;
    const int m0   = blockIdx.x * 32;          // global row base (b*4096+s0)
    const int b    = m0 >> 12;
    const int s0   = m0 & 4095;
    const int tile = s0 >> 6;
    const int thalf = s0 & 32;                 // row offset within kv tile

    f32x4 acc[2][3];
    #pragma unroll
    for (int i = 0; i < 2; i++)
        #pragma unroll
        for (int j = 0; j < 3; j++)
            #pragma unroll
            for (int r = 0; r < 4; r++) acc[i][j][r] = 0.f;

    // prologue: stage x tile for kt=0 into buf0 (512 float4 / 256 thr)
    {
        #pragma unroll
        for (int i = 0; i < 2; i++) {
            int c = tid + i * 256;
            int row = c >> 4, c16 = c & 15;
            float4 v = *(const float4*)(x + (size_t)(m0 + row) * DMODEL + c16 * 4);
            float vv[4] = {v.x, v.y, v.z, v.w};
            ushort4v hh, ll;
            #pragma unroll
            for (int j = 0; j < 4; j++) {
                unsigned short h1 = f2bf(vv[j]);
                hh[j] = h1; ll[j] = f2bf(vv[j] - bf2f(h1));
            }
            int ba = swz(row, c16 * 8);
            *(ushort4v*)(sm + ba) = hh;
            *(ushort4v*)(sm + 4096 + ba) = ll;
        }
        __syncthreads();
    }

    for (int kt = 0; kt < 16; ++kt) {
        const int cur = kt & 1;
        unsigned char* xh = sm + cur * 8192;
        unsigned char* xl = xh + 4096;
        const bool last = (kt == 15);
        // W fragments for this kt (reg-direct, L2/L3-resident)
        short8 wfh[2][3], wfl[2][3];
        #pragma unroll
        for (int ks = 0; ks < 2; ks++)
            #pragma unroll
            for (int ns = 0; ns < 3; ns++) {
                int rown = w * 48 + ns * 16 + (lane & 15);
                size_t kb = (size_t)kt * 8 + ks * 4 + (lane >> 4);
                wfh[ks][ns] = *(const short8*)(WHp + kb * 1536 + rown * 8);
                wfl[ks][ns] = *(const short8*)(WLp + kb * 1536 + rown * 8);
            }
        // x loads for kt+1 (consumed after MFMA)
        float4 xn[2];
        if (!last) {
            #pragma unroll
            for (int i = 0; i < 2; i++) {
                int c = tid + i * 256;
                int row = c >> 4, c16 = c & 15;
                xn[i] = *(const float4*)(x + (size_t)(m0 + row) * DMODEL + (kt + 1) * 64 + c16 * 4);
            }
        }
        // MFMA over current buffers
        #pragma unroll
        for (int ks = 0; ks < 2; ks++) {
            short8 ah[2], al[2];
            #pragma unroll
            for (int ms = 0; ms < 2; ms++) {
                int rowm = ms * 16 + (lane & 15);
                int off  = ks * 64 + ((lane >> 4) << 4);
                ah[ms] = *(const short8*)(xh + swz(rowm, off));
                al[ms] = *(const short8*)(xl + swz(rowm, off));
            }
            #pragma unroll
            for (int ns = 0; ns < 3; ns++) {
                #pragma unroll
                for (int ms = 0; ms < 2; ms++) {
                    acc[ms][ns] = __builtin_amdgcn_mfma_f32_16x16x32_bf16(ah[ms], wfh[ks][ns], acc[ms][ns], 0, 0, 0);
                    acc[ms][ns] = __builtin_amdgcn_mfma_f32_16x16x32_bf16(ah[ms], wfl[ks][ns], acc[ms][ns], 0, 0, 0);
                    acc[ms][ns] = __builtin_amdgcn_mfma_f32_16x16x32_bf16(al[ms], wfh[ks][ns], acc[ms][ns], 0, 0, 0);
                }
            }
        }
        // split next x tile into the other buffer
        if (!last) {
            unsigned char* nh = sm + (cur ^ 1) * 8192;
            unsigned char* nl = nh + 4096;
            #pragma unroll
            for (int i = 0; i < 2; i++) {
                int c = tid + i * 256;
                int row = c >> 4, c16 = c & 15;
                float vv[4] = {xn[i].x, xn[i].y, xn[i].z, xn[i].w};
                ushort4v hh, ll;
                #pragma unroll
                for (int j = 0; j < 4; j++) {
                    unsigned short h1 = f2bf(vv[j]);
                    hh[j] = h1; ll[j] = f2bf(vv[j] - bf2f(h1));
                }
                int ba = swz(row, c16 * 8);
                *(ushort4v*)(nh + ba) = hh;
                *(ushort4v*)(nl + ba) = ll;
            }
        }
        __syncthreads();
    }

    // epilogue: C/D 16x16 layout: col = lane&15, row = (lane>>4)*4 + r
    #pragma unroll
    for (int ms = 0; ms < 2; ms++) {
        #pragma unroll
        for (int ns = 0; ns < 3; ns++) {
            int c   = w * 48 + ns * 16 + (lane & 15);
            int mat = c >> 6;                 // 0=Q 1=K 2=V (uniform per w,ns)
            int dk  = c & 63;
            int rb  = ms * 16 + ((lane >> 4) << 2);
            const size_t tb = (size_t)(b * 64 + tile) * 16384;
            if (mat == 0) {                   // Q: plain [b][s][64], pre-scaled
                #pragma unroll
                for (int r = 0; r < 4; r++) {
                    float v = acc[ms][ns][r] * QSCALE;
                    size_t o = (size_t)(m0 + rb + r) * DHEAD + dk;
                    unsigned short hh = f2bf(v);
                    QH[o] = hh; QL[o] = f2bf(v - bf2f(hh));
                }
            } else if (mat == 1) {            // K: KV parts 0(hi),1(lo), rows=kv
                #pragma unroll
                for (int r = 0; r < 4; r++) {
                    float v = acc[ms][ns][r];
                    int row = thalf + rb + r;
                    size_t o = tb + row * 64 + (dk ^ ((row & 7) << 3));
                    unsigned short hh = f2bf(v);
                    KV[o] = hh; KV[o + 4096] = f2bf(v - bf2f(hh));
                }
            } else {                          // V: parts 2,3, rows=dk (V^T)
                ushort4v h, l;
                #pragma unroll
                for (int r = 0; r < 4; r++) {
                    float v = acc[ms][ns][r];
                    unsigned short hh = f2bf(v);
                    h[r] = hh; l[r] = f2bf(v - bf2f(hh));
                }
                int col = thalf + rb;          // 4-aligned; XOR keeps contiguity
                size_t o = tb + 8192 + dk * 64 + (col ^ ((dk & 7) << 3));
                *(ushort4v*)(KV + o) = h;
                *(ushort4v*)(KV + o + 4096) = l;
            }
        }
    }
}

// ---------------------------------------------------------------- kernel 2 --
// Flash chunk: QB=128, 4 waves (wave w = q rows [q0+32w, +32)), KVB=64.
// Swapped QK^T: sacc = S^T (col=lane&31 = q, rows = kv). Scalar m/l per lane.
// KV double-buffered in LDS; stage of t+1 issued BEFORE compute of t.
__global__ __launch_bounds__(256, 2)
void attn_kernel(const unsigned short* __restrict__ QH, const unsigned short* __restrict__ QL,
                 const unsigned short* __restrict__ KV,
                 float* __restrict__ OP, float* __restrict__ ML,
                 float* __restrict__ out)
{
    __shared__ unsigned char sm[65536];        // 2 x [KH 8K][KL 8K][VH 8K][VL 8K]
    const int tid  = threadIdx.x;
    const int lane = tid & 63;
    const int hi   = lane >> 5;
    const int w    = tid >> 6;
    const int b    = blockIdx.x & 7;           // batch == XCD slot: KV L2-local
    const int c    = 79 - (int)(blockIdx.x >> 3);  // big chunks first
    int qb, ch;
    if      (c < 8)  { qb = c;                ch = 0; }
    else if (c < 24) { qb = 8 + ((c - 8) >> 1);  ch = (c - 8) & 1; }
    else if (c < 48) { qb = 16 + (c - 24) / 3;   ch = (c - 24) % 3; }
    else             { qb = 24 + ((c - 48) >> 2); ch = (c - 48) & 3; }
    const int nt   = 2 * qb + 2;
    const int t0   = ch * 16;
    const int tend = min(t0 + 16, nt);
    const int nc   = (qb < 8) ? 1 : ((qb < 16) ? 2 : ((qb < 24) ? 3 : 4));
    const int q0   = qb * 128;
    const int qABase = q0 + w * 32;            // wave's lowest q row
    const int qi     = qABase + (lane & 31);   // this lane's q row

    // Q fragments (B-operand: col=q, k=hi*8+j), straight from global
    short8 qh[4], ql[4];
    {
        const size_t qrow = (size_t)(b * SEQ + qi) * DHEAD;
        #pragma unroll
        for (int ks = 0; ks < 4; ks++) {
            int off = ks * 16 + hi * 8;
            qh[ks] = *(const short8*)(QH + qrow + off);
            ql[ks] = *(const short8*)(QL + qrow + off);
        }
    }

    f32x16 oacc[2];                            // O^T: col=q, rows=d (+32*dsub)
    #pragma unroll
    for (int r = 0; r < 16; r++) { oacc[0][r] = 0.f; oacc[1][r] = 0.f; }
    float m_s = M_INIT, l_s = 0.f;

    // prologue: stage first tile into buf0
    {
        const unsigned short* src = KV + (size_t)(b * 64 + t0) * 16384 + w * 4096 + lane * 8;
        unsigned char* dst = sm + w * 8192;
        #pragma unroll
        for (int i = 0; i < 8; i++)
            gload16(src + i * 512, dst + i * 1024);
    }
    asm volatile("s_waitcnt vmcnt(0)" ::: "memory");
    __syncthreads();

    for (int t = t0; t < tend; ++t) {
        const int cur = (t - t0) & 1;
        unsigned char* buf = sm + cur * 32768;
        // issue-early: stage tile t+1 into the other buffer (T14/T3 depth-1)
        if (t + 1 < tend) {
            const unsigned short* src = KV + (size_t)(b * 64 + t + 1) * 16384 + w * 4096 + lane * 8;
            unsigned char* dst = sm + (cur ^ 1) * 32768 + w * 8192;
            #pragma unroll
            for (int i = 0; i < 8; i++)
                gload16(src + i * 512, dst + i * 1024);
        }
        const int kv0 = t * 64;

        if (kv0 <= qABase + 31) {              // wave has unmasked rows here
            // ---- S^T = K Q^T  (A=K rows=kv, B=Q cols=q) ----
            f32x16 sacc[2];
            #pragma unroll
            for (int r = 0; r < 16; r++) { sacc[0][r] = 0.f; sacc[1][r] = 0.f; }
            #pragma unroll
            for (int sub = 0; sub < 2; sub++) {
                int row = sub * 32 + (lane & 31);
                #pragma unroll
                for (int ks = 0; ks < 4; ks++) {
                    int off = ks * 32 + hi * 16;
                    short8 kh = *(const short8*)(buf + swz(row, off));
                    short8 kl = *(const short8*)(buf + 8192 + swz(row, off));
                    sacc[sub] = __builtin_amdgcn_mfma_f32_32x32x16_bf16(kh, qh[ks], sacc[sub], 0, 0, 0);
                    sacc[sub] = __builtin_amdgcn_mfma_f32_32x32x16_bf16(kh, ql[ks], sacc[sub], 0, 0, 0);
                    sacc[sub] = __builtin_amdgcn_mfma_f32_32x32x16_bf16(kl, qh[ks], sacc[sub], 0, 0, 0);
                }
            }

            // ---- causal mask (finite sentinel) ----
            if (kv0 + 63 > qABase) {
                #pragma unroll
                for (int sub = 0; sub < 2; sub++)
                    #pragma unroll
                    for (int r = 0; r < 16; r++) {
                        int kvg = kv0 + sub * 32 + (r & 3) + 8 * (r >> 2) + 4 * hi;
                        if (kvg > qi) sacc[sub][r] = MASK_S;
                    }
            }

            // ---- in-register online softmax (per-lane scalars) ----
            float vm = sacc[0][0];
            #pragma unroll
            for (int sub = 0; sub < 2; sub++)
                #pragma unroll
                for (int r = 0; r < 16; r++) vm = fmaxf(vm, sacc[sub][r]);
            vm = fmaxf(vm, __shfl_xor(vm, 32));
            const float mnew = fmaxf(m_s, vm);
            const float alff = __builtin_amdgcn_exp2f(m_s - mnew);
            m_s = mnew;
            float rs = 0.f;
            #pragma unroll
            for (int sub = 0; sub < 2; sub++)
                #pragma unroll
                for (int r = 0; r < 16; r++) {
                    float p = __builtin_amdgcn_exp2f(sacc[sub][r] - mnew);
                    sacc[sub][r] = p;
                    rs += p;
                }
            rs += __shfl_xor(rs, 32);
            l_s = l_s * alff + rs;
            #pragma unroll
            for (int r = 0; r < 16; r++) { oacc[0][r] *= alff; oacc[1][r] *= alff; }

            // ---- P -> bf16 hi/lo frags + PV (O^T += V^T P^T) ----
            #pragma unroll
            for (int ks = 0; ks < 4; ks++) {
                const int sub = ks >> 1, rb = (ks & 1) * 8;
                float v0 = sacc[sub][rb + 0], v1 = sacc[sub][rb + 1];
                float v2 = sacc[sub][rb + 2], v3 = sacc[sub][rb + 3];
                float v4 = sacc[sub][rb + 4], v5 = sacc[sub][rb + 5];
                float v6 = sacc[sub][rb + 6], v7 = sacc[sub][rb + 7];
                unsigned Ah0 = cvtpk(v0, v1), Ah1 = cvtpk(v2, v3);
                unsigned Bh0 = cvtpk(v4, v5), Bh1 = cvtpk(v6, v7);
                float l0 = v0 - asf(Ah0 << 16), l1 = v1 - asf(Ah0 & 0xffff0000u);
                float l2 = v2 - asf(Ah1 << 16), l3 = v3 - asf(Ah1 & 0xffff0000u);
                float l4 = v4 - asf(Bh0 << 16), l5 = v5 - asf(Bh0 & 0xffff0000u);
                float l6 = v6 - asf(Bh1 << 16), l7 = v7 - asf(Bh1 & 0xffff0000u);
                unsigned Al0 = cvtpk(l0, l1), Al1 = cvtpk(l2, l3);
                unsigned Bl0 = cvtpk(l4, l5), Bl1 = cvtpk(l6, l7);
                // exchange: hi=0 sends B(kv8-11), gets partner A(kv4-7); hi=1 opp.
                unsigned eh0 = __shfl_xor(hi ? Ah0 : Bh0, 32);
                unsigned eh1 = __shfl_xor(hi ? Ah1 : Bh1, 32);
                unsigned el0 = __shfl_xor(hi ? Al0 : Bl0, 32);
                unsigned el1 = __shfl_xor(hi ? Al1 : Bl1, 32);
                short8 PH = hi ? mk8(eh0, eh1, Bh0, Bh1) : mk8(Ah0, Ah1, eh0, eh1);
                short8 PL = hi ? mk8(el0, el1, Bl0, Bl1) : mk8(Al0, Al1, el0, el1);
                const int off = ks * 32 + hi * 16;
                #pragma unroll
                for (int dsub = 0; dsub < 2; dsub++) {
                    int vrow = dsub * 32 + (lane & 31);
                    short8 vh = *(const short8*)(buf + 16384 + swz(vrow, off));
                    short8 vl = *(const short8*)(buf + 24576 + swz(vrow, off));
                    oacc[dsub] = __builtin_amdgcn_mfma_f32_32x32x16_bf16(vh, PH, oacc[dsub], 0, 0, 0);
                    oacc[dsub] = __builtin_amdgcn_mfma_f32_32x32x16_bf16(vh, PL, oacc[dsub], 0, 0, 0);
                    oacc[dsub] = __builtin_amdgcn_mfma_f32_32x32x16_bf16(vl, PH, oacc[dsub], 0, 0, 0);
                }
            }
        }

        // wait for t+1's staged loads (had the whole compute to land) + fence
        asm volatile("s_waitcnt vmcnt(0)" ::: "memory");
        __syncthreads();
    }

    // ---- epilogue: O^T cols=q, rows d = dsub*32 + 8*rg + 4*hi + (r&3) ----
    if (nc == 1) {
        const float inv = 1.f / l_s;
        float* orow = out + (size_t)(b * SEQ + qi) * DHEAD;
        #pragma unroll
        for (int dsub = 0; dsub < 2; dsub++)
            #pragma unroll
            for (int rg = 0; rg < 4; rg++) {
                f32x4 v;
                #pragma unroll
                for (int j = 0; j < 4; j++) v[j] = oacc[dsub][rg * 4 + j] * inv;
                *(f32x4*)(orow + dsub * 32 + rg * 8 + hi * 4) = v;
            }
    } else {
        const size_t cbase = (size_t)((b * 32 + qb) * 4 + ch);
        float* orow = OP + cbase * 8192 + (size_t)(w * 32 + (lane & 31)) * 64;
        #pragma unroll
        for (int dsub = 0; dsub < 2; dsub++)
            #pragma unroll
            for (int rg = 0; rg < 4; rg++) {
                f32x4 v;
                #pragma unroll
                for (int j = 0; j < 4; j++) v[j] = oacc[dsub][rg * 4 + j];
                *(f32x4*)(orow + dsub * 32 + rg * 8 + hi * 4) = v;
            }
        if (hi == 0) {
            size_t o = cbase * 256 + (size_t)(w * 32 + lane) * 2;
            ML[o] = m_s; ML[o + 1] = l_s;
        }
    }
}

// ---------------------------------------------------------------- kernel 3 --
// Merge chunks for qb >= 8 (2..4 chunks). grid 8*24, 256 thr. exp2 domain.
__global__ __launch_bounds__(256, 4)
void combine_kernel(const float* __restrict__ OP, const float* __restrict__ ML,
                    float* __restrict__ out)
{
    const int b   = blockIdx.x & 7;
    const int qb  = 8 + (int)(blockIdx.x >> 3);
    const int nc  = (qb < 16) ? 2 : ((qb < 24) ? 3 : 4);
    const int qlo = threadIdx.x >> 1;          // 0..127
    const int d0  = (threadIdx.x & 1) * 32;
    const size_t cbase = (size_t)(b * 32 + qb) * 4;

    float mv[4], lv[4];
    float M = MASK_S;
    #pragma unroll
    for (int ch = 0; ch < 4; ch++) if (ch < nc) {
        mv[ch] = ML[(cbase + ch) * 256 + qlo * 2];
        lv[ch] = ML[(cbase + ch) * 256 + qlo * 2 + 1];
        M = fmaxf(M, mv[ch]);
    }
    float L = 0.f, sc[4];
    #pragma unroll
    for (int ch = 0; ch < 4; ch++) if (ch < nc) {
        sc[ch] = __builtin_amdgcn_exp2f(mv[ch] - M);
        L += lv[ch] * sc[ch];
    }
    const float inv = 1.f / L;

    f32x4 acc[8];
    #pragma unroll
    for (int j = 0; j < 8; j++) { acc[j][0] = 0.f; acc[j][1] = 0.f; acc[j][2] = 0.f; acc[j][3] = 0.f; }
    #pragma unroll
    for (int ch = 0; ch < 4; ch++) if (ch < nc) {
        const float* bp = OP + (cbase + ch) * 8192 + (size_t)qlo * 64 + d0;
        #pragma unroll
        for (int j = 0; j < 8; j++) acc[j] += *(const f32x4*)(bp + j * 4) * sc[ch];
    }
    float* ob = out + (size_t)(b * SEQ + qb * 128 + qlo) * 64 + d0;
    #pragma unroll
    for (int j = 0; j < 8; j++) *(f32x4*)(ob + j * 4) = acc[j] * inv;
}

// ------------------------------------------------------------------- launch --
extern "C" void kernel_launch(void* const* d_in, const int* in_sizes, int n_in,
                              void* d_out, int out_size, void* d_ws, size_t ws_size,
                              hipStream_t stream)
{
    const float* x  = (const float*)d_in[0];
    const float* wQ = (const float*)d_in[1];
    const float* wK = (const float*)d_in[2];
    const float* wV = (const float*)d_in[3];
    float* out = (float*)d_out;

    // workspace: W 0.75MB + Q 8.4MB + KV 16.8MB + OP 33.5MB + ML 1MB ~= 60.5MB
    unsigned short* p   = (unsigned short*)d_ws;
    unsigned short* WHp = p; p += 192 * 1024;
    unsigned short* WLp = p; p += 192 * 1024;
    unsigned short* QHp = p; p += 8 * 4096 * 64;
    unsigned short* QLp = p; p += 8 * 4096 * 64;
    unsigned short* KVp = p; p += (size_t)8 * 64 * 16384;
    float* fp = (float*)p;
    float* OP = fp; fp += (size_t)8 * 32 * 4 * 8192;   // partial O
    float* ML = fp; fp += (size_t)8 * 32 * 4 * 256;    // (m,l)

    splitw_kernel<<<dim3(192), dim3(256), 0, stream>>>(wQ, wK, wV, WHp, WLp);
    proj_kernel<<<dim3(1024), dim3(256), 0, stream>>>(x, WHp, WLp, QHp, QLp, KVp);
    attn_kernel<<<dim3(640), dim3(256), 0, stream>>>(QHp, QLp, KVp, OP, ML, out);
    combine_kernel<<<dim3(192), dim3(256), 0, stream>>>(OP, ML, out);
}

// Round 5
// 304.542 us; speedup vs baseline: 2.4141x; 1.0519x over previous
//
#include <hip/hip_runtime.h>
#include <hip/hip_bf16.h>

// ============================================================================
// AttentionHead (B=8,S=4096,D=1024,DK=64), fp32 in/out — MI355X gfx950
// R5: attn with NO LDS — K/V stored in MFMA-fragment order by proj, loaded
//     global->VGPR fully coalesced; 1-wave blocks, no barriers, 12 waves/CU.
// Precision: split-bf16 (hi+lo) x 3-product MFMA => ~fp32 accuracy.
// K0 splitw : W -> bf16 hi/lo, k-chunked [kb][192][8] layout
// K1 proj   : Q (pre-scaled by dm^-.5*log2e); K/V -> per-tile FRAGMENT layout:
//             tile(32KB ushort[16384]) = [KH][KL][VH][VL], each 4096 ushorts
//             as [sub(2)][ks(4)][lane(64)][8]:
//               K: lane=hi*32+(kvrow&31), frag = K[kvrow][ks*16+hi*8 .. +8)
//               V: lane=hi*32+(d&31),     frag = V^T[d][ks*16+hi*8 .. +8)
// K2 attn   : flash chunk, 1 wave = 32 q rows, KVB=64, 32x32x16 bf16 MFMA,
//             swapped QK^T (S^T in regs), scalar m/l per lane
// K3 combine: merge partial (O,m,l) chunks (exp2 domain)
// ============================================================================

typedef __attribute__((ext_vector_type(8)))  short   short8;
typedef __attribute__((ext_vector_type(4)))  float   f32x4;
typedef __attribute__((ext_vector_type(16))) float   f32x16;
typedef __attribute__((ext_vector_type(4)))  unsigned short ushort4v;

#define DEV static __device__ __forceinline__

constexpr int SEQ    = 4096;
constexpr int DMODEL = 1024;
constexpr int DHEAD  = 64;
// fold d_model^-0.5 AND log2(e) into Q so attn uses exp2 directly
constexpr float QSCALE = 0.03125f * 1.44269504088896340736f;
constexpr float MASK_S = -30000.f;   // masked score (log2 domain), finite
constexpr float M_INIT = -10000.f;   // running-max init; MASK_S - M_INIT << 0

DEV unsigned short f2bf(float x) {           // fp32 -> bf16 RNE
    union { float f; unsigned u; } v; v.f = x;
    unsigned r = v.u + 0x7fffu + ((v.u >> 16) & 1u);
    return (unsigned short)(r >> 16);
}
DEV float bf2f(unsigned short h) {
    union { unsigned u; float f; } v; v.u = ((unsigned)h) << 16;
    return v.f;
}
DEV float asf(unsigned u) { union { unsigned u; float f; } v; v.u = u; return v.f; }
// byte address inside a [rows][64]bf16 tile (pitch 128B) with XOR swizzle
DEV int swz(int row, int off) { return row * 128 + (off ^ ((row & 7) << 4)); }

DEV unsigned cvtpk(float lo, float hi) {     // pack 2 fp32 -> 2 bf16 (lo|hi<<16)
    unsigned r;
    asm("v_cvt_pk_bf16_f32 %0, %1, %2" : "=v"(r) : "v"(lo), "v"(hi));
    return r;
}
DEV short8 mk8(unsigned a, unsigned b, unsigned c, unsigned d) {
    union { unsigned u[4]; short8 s; } x;
    x.u[0] = a; x.u[1] = b; x.u[2] = c; x.u[3] = d; return x.s;
}

// ---------------------------------------------------------------- kernel 0 --
// W -> bf16 hi/lo, layout [kb=k/8][row 0..191][8]  (coalesced frag reads)
__global__ void splitw_kernel(const float* __restrict__ wQ,
                              const float* __restrict__ wK,
                              const float* __restrict__ wV,
                              unsigned short* __restrict__ WHp,
                              unsigned short* __restrict__ WLp)
{
    int t   = blockIdx.x * 256 + threadIdx.x;  // 49152 float4 chunks, exact
    int fl  = t * 4;
    int row = fl >> 10;                        // 0..191 (Q,K,V stacked)
    int k   = fl & 1023;
    const float* src = (row < 64) ? wQ : (row < 128 ? wK : wV);
    float4 v = *(const float4*)(src + (row & 63) * 1024 + k);
    float vv[4] = {v.x, v.y, v.z, v.w};
    ushort4v h, l;
    #pragma unroll
    for (int j = 0; j < 4; j++) {
        unsigned short hh = f2bf(vv[j]);
        h[j] = hh;
        l[j] = f2bf(vv[j] - bf2f(hh));
    }
    size_t u = (size_t)(k >> 3) * 1536 + row * 8 + (k & 7);
    *(ushort4v*)(WHp + u) = h;
    *(ushort4v*)(WLp + u) = l;
}

// ---------------------------------------------------------------- kernel 1 --
// M=32 rows/block, 1024 blocks (4/CU), 4 waves; wave w owns cols [48w,48w+48).
// K-step 64, 16 iters. W frags reg-direct from global; x dbuf in LDS (16KB).
__global__ __launch_bounds__(256, 4)
void proj_kernel(const float* __restrict__ x,
                 const unsigned short* __restrict__ WHp,
                 const unsigned short* __restrict__ WLp,
                 unsigned short* __restrict__ QH, unsigned short* __restrict__ QL,
                 unsigned short* __restrict__ KV)
{
    __shared__ unsigned char sm[16384];        // dbuf: [cur][hi 4KB | lo 4KB]
    const int tid  = threadIdx.x;
    const int lane = tid & 63;
    const int w    = tid >> 6;
    const int m0   = blockIdx.x * 32;          // global row base (b*4096+s0)
    const int b    = m0 >> 12;
    const int s0   = m0 & 4095;
    const int tile = s0 >> 6;
    const int thalf = s0 & 32;                 // row offset within kv tile

    f32x4 acc[2][3];
    #pragma unroll
    for (int i = 0; i < 2; i++)
        #pragma unroll
        for (int j = 0; j < 3; j++)
            #pragma unroll
            for (int r = 0; r < 4; r++) acc[i][j][r] = 0.f;

    // prologue: stage x tile for kt=0 into buf0 (512 float4 / 256 thr)
    {
        #pragma unroll
        for (int i = 0; i < 2; i++) {
            int c = tid + i * 256;
            int row = c >> 4, c16 = c & 15;
            float4 v = *(const float4*)(x + (size_t)(m0 + row) * DMODEL + c16 * 4);
            float vv[4] = {v.x, v.y, v.z, v.w};
            ushort4v hh, ll;
            #pragma unroll
            for (int j = 0; j < 4; j++) {
                unsigned short h1 = f2bf(vv[j]);
                hh[j] = h1; ll[j] = f2bf(vv[j] - bf2f(h1));
            }
            int ba = swz(row, c16 * 8);
            *(ushort4v*)(sm + ba) = hh;
            *(ushort4v*)(sm + 4096 + ba) = ll;
        }
        __syncthreads();
    }

    for (int kt = 0; kt < 16; ++kt) {
        const int cur = kt & 1;
        unsigned char* xh = sm + cur * 8192;
        unsigned char* xl = xh + 4096;
        const bool last = (kt == 15);
        // W fragments for this kt (reg-direct, L2/L3-resident)
        short8 wfh[2][3], wfl[2][3];
        #pragma unroll
        for (int ks = 0; ks < 2; ks++)
            #pragma unroll
            for (int ns = 0; ns < 3; ns++) {
                int rown = w * 48 + ns * 16 + (lane & 15);
                size_t kb = (size_t)kt * 8 + ks * 4 + (lane >> 4);
                wfh[ks][ns] = *(const short8*)(WHp + kb * 1536 + rown * 8);
                wfl[ks][ns] = *(const short8*)(WLp + kb * 1536 + rown * 8);
            }
        // x loads for kt+1 (consumed after MFMA)
        float4 xn[2];
        if (!last) {
            #pragma unroll
            for (int i = 0; i < 2; i++) {
                int c = tid + i * 256;
                int row = c >> 4, c16 = c & 15;
                xn[i] = *(const float4*)(x + (size_t)(m0 + row) * DMODEL + (kt + 1) * 64 + c16 * 4);
            }
        }
        // MFMA over current buffers
        #pragma unroll
        for (int ks = 0; ks < 2; ks++) {
            short8 ah[2], al[2];
            #pragma unroll
            for (int ms = 0; ms < 2; ms++) {
                int rowm = ms * 16 + (lane & 15);
                int off  = ks * 64 + ((lane >> 4) << 4);
                ah[ms] = *(const short8*)(xh + swz(rowm, off));
                al[ms] = *(const short8*)(xl + swz(rowm, off));
            }
            #pragma unroll
            for (int ns = 0; ns < 3; ns++) {
                #pragma unroll
                for (int ms = 0; ms < 2; ms++) {
                    acc[ms][ns] = __builtin_amdgcn_mfma_f32_16x16x32_bf16(ah[ms], wfh[ks][ns], acc[ms][ns], 0, 0, 0);
                    acc[ms][ns] = __builtin_amdgcn_mfma_f32_16x16x32_bf16(ah[ms], wfl[ks][ns], acc[ms][ns], 0, 0, 0);
                    acc[ms][ns] = __builtin_amdgcn_mfma_f32_16x16x32_bf16(al[ms], wfh[ks][ns], acc[ms][ns], 0, 0, 0);
                }
            }
        }
        // split next x tile into the other buffer
        if (!last) {
            unsigned char* nh = sm + (cur ^ 1) * 8192;
            unsigned char* nl = nh + 4096;
            #pragma unroll
            for (int i = 0; i < 2; i++) {
                int c = tid + i * 256;
                int row = c >> 4, c16 = c & 15;
                float vv[4] = {xn[i].x, xn[i].y, xn[i].z, xn[i].w};
                ushort4v hh, ll;
                #pragma unroll
                for (int j = 0; j < 4; j++) {
                    unsigned short h1 = f2bf(vv[j]);
                    hh[j] = h1; ll[j] = f2bf(vv[j] - bf2f(h1));
                }
                int ba = swz(row, c16 * 8);
                *(ushort4v*)(nh + ba) = hh;
                *(ushort4v*)(nl + ba) = ll;
            }
        }
        __syncthreads();
    }

    // epilogue: C/D 16x16 layout: col = lane&15, row = (lane>>4)*4 + r
    // K/V written in attn FRAGMENT order (see header comment).
    #pragma unroll
    for (int ms = 0; ms < 2; ms++) {
        #pragma unroll
        for (int ns = 0; ns < 3; ns++) {
            int c   = w * 48 + ns * 16 + (lane & 15);
            int mat = c >> 6;                 // 0=Q 1=K 2=V (uniform per w,ns)
            int dk  = c & 63;
            int rb  = ms * 16 + ((lane >> 4) << 2);
            const size_t tb = (size_t)(b * 64 + tile) * 16384;
            if (mat == 0) {                   // Q: plain [b][s][64], pre-scaled
                #pragma unroll
                for (int r = 0; r < 4; r++) {
                    float v = acc[ms][ns][r] * QSCALE;
                    size_t o = (size_t)(m0 + rb + r) * DHEAD + dk;
                    unsigned short hh = f2bf(v);
                    QH[o] = hh; QL[o] = f2bf(v - bf2f(hh));
                }
            } else if (mat == 1) {            // K frag: sub=row>>5, ks=dk>>4
                const int ks = dk >> 4, hj = (dk >> 3) & 1, j = dk & 7;
                #pragma unroll
                for (int r = 0; r < 4; r++) {
                    float v = acc[ms][ns][r];
                    int row = thalf + rb + r;
                    size_t o = tb + (size_t)(((row >> 5) * 4 + ks) * 512
                                 + (hj * 32 + (row & 31)) * 8 + j);
                    unsigned short hh = f2bf(v);
                    KV[o] = hh; KV[o + 4096] = f2bf(v - bf2f(hh));
                }
            } else {                          // V frag: dsub=dk>>5, ks=col>>4
                ushort4v h, l;
                #pragma unroll
                for (int r = 0; r < 4; r++) {
                    float v = acc[ms][ns][r];
                    unsigned short hh = f2bf(v);
                    h[r] = hh; l[r] = f2bf(v - bf2f(hh));
                }
                const int col = thalf + rb;   // 4-aligned kv position
                const int ks = col >> 4, hj = (col >> 3) & 1, jb = col & 4;
                size_t o = tb + 8192 + (size_t)((((dk >> 5) * 4 + ks) * 512
                             + (hj * 32 + (dk & 31)) * 8 + jb));
                *(ushort4v*)(KV + o) = h;
                *(ushort4v*)(KV + o + 4096) = l;
            }
        }
    }
}

// ---------------------------------------------------------------- kernel 2 --
// Flash chunk, NO LDS: 1 wave per block = 32 q rows; KVB=64; frags loaded
// global->reg coalesced from the fragment-ordered KV workspace.
// Swapped QK^T: sacc = S^T (col=lane&31 = q, rows = kv). Scalar m/l per lane.
__global__ __launch_bounds__(64, 3)
void attn_kernel(const unsigned short* __restrict__ QH, const unsigned short* __restrict__ QL,
                 const unsigned short* __restrict__ KV,
                 float* __restrict__ OP, float* __restrict__ ML,
                 float* __restrict__ out)
{
    const int lane = threadIdx.x;              // 0..63
    const int hi   = lane >> 5;
    const int b    = blockIdx.x & 7;           // batch == XCD slot: KV L2-local
    const int idx  = (int)(blockIdx.x >> 3);   // 0..319
    const int w    = idx & 3;                  // q sub-block within QB=128
    const int c    = 79 - (idx >> 2);          // big chunks first
    int qb, ch;
    if      (c < 8)  { qb = c;                ch = 0; }
    else if (c < 24) { qb = 8 + ((c - 8) >> 1);  ch = (c - 8) & 1; }
    else if (c < 48) { qb = 16 + (c - 24) / 3;   ch = (c - 24) % 3; }
    else             { qb = 24 + ((c - 48) >> 2); ch = (c - 48) & 3; }
    const int nc   = (qb < 8) ? 1 : ((qb < 16) ? 2 : ((qb < 24) ? 3 : 4));
    const int q0   = qb * 128;
    const int qABase = q0 + w * 32;            // wave's lowest q row
    const int qi     = qABase + (lane & 31);   // this lane's q row
    const int t0   = ch * 16;
    const int tend = min(t0 + 16, ((qABase + 31) >> 6) + 1);  // per-wave diag

    // Q fragments (B-operand: col=q, k=hi*8+j), straight from global
    short8 qh[4], ql[4];
    {
        const size_t qrow = (size_t)(b * SEQ + qi) * DHEAD;
        #pragma unroll
        for (int ks = 0; ks < 4; ks++) {
            int off = ks * 16 + hi * 8;
            qh[ks] = *(const short8*)(QH + qrow + off);
            ql[ks] = *(const short8*)(QL + qrow + off);
        }
    }

    f32x16 oacc[2];                            // O^T: col=q, rows=d (+32*dsub)
    #pragma unroll
    for (int r = 0; r < 16; r++) { oacc[0][r] = 0.f; oacc[1][r] = 0.f; }
    float m_s = M_INIT, l_s = 0.f;

    for (int t = t0; t < tend; ++t) {
        const int kv0 = t * 64;
        const unsigned short* KF = KV + (size_t)(b * 64 + t) * 16384 + lane * 8;

        // ---- S^T = K Q^T ---- (K frags coalesced: 16B/lane, 1KB/instr)
        f32x16 sacc[2];
        #pragma unroll
        for (int r = 0; r < 16; r++) { sacc[0][r] = 0.f; sacc[1][r] = 0.f; }
        #pragma unroll
        for (int sub = 0; sub < 2; sub++) {
            short8 kh[4], kl[4];
            #pragma unroll
            for (int ks = 0; ks < 4; ks++) {
                kh[ks] = *(const short8*)(KF + (sub * 4 + ks) * 512);
                kl[ks] = *(const short8*)(KF + 4096 + (sub * 4 + ks) * 512);
            }
            #pragma unroll
            for (int ks = 0; ks < 4; ks++) {
                sacc[sub] = __builtin_amdgcn_mfma_f32_32x32x16_bf16(kh[ks], qh[ks], sacc[sub], 0, 0, 0);
                sacc[sub] = __builtin_amdgcn_mfma_f32_32x32x16_bf16(kh[ks], ql[ks], sacc[sub], 0, 0, 0);
                sacc[sub] = __builtin_amdgcn_mfma_f32_32x32x16_bf16(kl[ks], qh[ks], sacc[sub], 0, 0, 0);
            }
        }

        // issue V-hi loads now; latency hides under mask+softmax VALU
        short8 vh[2][4];
        #pragma unroll
        for (int dsub = 0; dsub < 2; dsub++)
            #pragma unroll
            for (int ks = 0; ks < 4; ks++)
                vh[dsub][ks] = *(const short8*)(KF + 8192 + (dsub * 4 + ks) * 512);

        // ---- causal mask (finite sentinel) ----
        if (kv0 + 63 > qABase) {
            #pragma unroll
            for (int sub = 0; sub < 2; sub++)
                #pragma unroll
                for (int r = 0; r < 16; r++) {
                    int kvg = kv0 + sub * 32 + (r & 3) + 8 * (r >> 2) + 4 * hi;
                    if (kvg > qi) sacc[sub][r] = MASK_S;
                }
        }

        // ---- in-register online softmax (per-lane scalars) ----
        float vm = sacc[0][0];
        #pragma unroll
        for (int sub = 0; sub < 2; sub++)
            #pragma unroll
            for (int r = 0; r < 16; r++) vm = fmaxf(vm, sacc[sub][r]);
        vm = fmaxf(vm, __shfl_xor(vm, 32));
        const float mnew = fmaxf(m_s, vm);
        const float alff = __builtin_amdgcn_exp2f(m_s - mnew);
        m_s = mnew;
        float rs = 0.f;
        #pragma unroll
        for (int sub = 0; sub < 2; sub++)
            #pragma unroll
            for (int r = 0; r < 16; r++) {
                float p = __builtin_amdgcn_exp2f(sacc[sub][r] - mnew);
                sacc[sub][r] = p;
                rs += p;
            }
        rs += __shfl_xor(rs, 32);
        l_s = l_s * alff + rs;
        #pragma unroll
        for (int r = 0; r < 16; r++) { oacc[0][r] *= alff; oacc[1][r] *= alff; }

        // ---- P -> bf16 hi/lo frags + PV (O^T += V^T P^T) ----
        #pragma unroll
        for (int ks = 0; ks < 4; ks++) {
            const int sub = ks >> 1, rb = (ks & 1) * 8;
            float v0 = sacc[sub][rb + 0], v1 = sacc[sub][rb + 1];
            float v2 = sacc[sub][rb + 2], v3 = sacc[sub][rb + 3];
            float v4 = sacc[sub][rb + 4], v5 = sacc[sub][rb + 5];
            float v6 = sacc[sub][rb + 6], v7 = sacc[sub][rb + 7];
            unsigned Ah0 = cvtpk(v0, v1), Ah1 = cvtpk(v2, v3);
            unsigned Bh0 = cvtpk(v4, v5), Bh1 = cvtpk(v6, v7);
            float l0 = v0 - asf(Ah0 << 16), l1 = v1 - asf(Ah0 & 0xffff0000u);
            float l2 = v2 - asf(Ah1 << 16), l3 = v3 - asf(Ah1 & 0xffff0000u);
            float l4 = v4 - asf(Bh0 << 16), l5 = v5 - asf(Bh0 & 0xffff0000u);
            float l6 = v6 - asf(Bh1 << 16), l7 = v7 - asf(Bh1 & 0xffff0000u);
            unsigned Al0 = cvtpk(l0, l1), Al1 = cvtpk(l2, l3);
            unsigned Bl0 = cvtpk(l4, l5), Bl1 = cvtpk(l6, l7);
            // exchange: hi=0 sends B(kv8-11), gets partner A(kv4-7); hi=1 opp.
            unsigned eh0 = __shfl_xor(hi ? Ah0 : Bh0, 32);
            unsigned eh1 = __shfl_xor(hi ? Ah1 : Bh1, 32);
            unsigned el0 = __shfl_xor(hi ? Al0 : Bl0, 32);
            unsigned el1 = __shfl_xor(hi ? Al1 : Bl1, 32);
            short8 PH = hi ? mk8(eh0, eh1, Bh0, Bh1) : mk8(Ah0, Ah1, eh0, eh1);
            short8 PL = hi ? mk8(el0, el1, Bl0, Bl1) : mk8(Al0, Al1, el0, el1);
            #pragma unroll
            for (int dsub = 0; dsub < 2; dsub++) {
                short8 vl = *(const short8*)(KF + 12288 + (dsub * 4 + ks) * 512);
                oacc[dsub] = __builtin_amdgcn_mfma_f32_32x32x16_bf16(vh[dsub][ks], PH, oacc[dsub], 0, 0, 0);
                oacc[dsub] = __builtin_amdgcn_mfma_f32_32x32x16_bf16(vh[dsub][ks], PL, oacc[dsub], 0, 0, 0);
                oacc[dsub] = __builtin_amdgcn_mfma_f32_32x32x16_bf16(vl, PH, oacc[dsub], 0, 0, 0);
            }
        }
    }

    // ---- epilogue: O^T cols=q, rows d = dsub*32 + 8*rg + 4*hi + (r&3) ----
    if (nc == 1) {
        const float inv = 1.f / l_s;
        float* orow = out + (size_t)(b * SEQ + qi) * DHEAD;
        #pragma unroll
        for (int dsub = 0; dsub < 2; dsub++)
            #pragma unroll
            for (int rg = 0; rg < 4; rg++) {
                f32x4 v;
                #pragma unroll
                for (int j = 0; j < 4; j++) v[j] = oacc[dsub][rg * 4 + j] * inv;
                *(f32x4*)(orow + dsub * 32 + rg * 8 + hi * 4) = v;
            }
    } else {
        const size_t cbase = (size_t)((b * 32 + qb) * 4 + ch);
        float* orow = OP + cbase * 8192 + (size_t)(w * 32 + (lane & 31)) * 64;
        #pragma unroll
        for (int dsub = 0; dsub < 2; dsub++)
            #pragma unroll
            for (int rg = 0; rg < 4; rg++) {
                f32x4 v;
                #pragma unroll
                for (int j = 0; j < 4; j++) v[j] = oacc[dsub][rg * 4 + j];
                *(f32x4*)(orow + dsub * 32 + rg * 8 + hi * 4) = v;
            }
        if (hi == 0) {
            size_t o = cbase * 256 + (size_t)(w * 32 + lane) * 2;
            ML[o] = m_s; ML[o + 1] = l_s;
        }
    }
}

// ---------------------------------------------------------------- kernel 3 --
// Merge chunks for qb >= 8 (2..4 chunks). grid 8*24, 256 thr. exp2 domain.
__global__ __launch_bounds__(256, 4)
void combine_kernel(const float* __restrict__ OP, const float* __restrict__ ML,
                    float* __restrict__ out)
{
    const int b   = blockIdx.x & 7;
    const int qb  = 8 + (int)(blockIdx.x >> 3);
    const int nc  = (qb < 16) ? 2 : ((qb < 24) ? 3 : 4);
    const int qlo = threadIdx.x >> 1;          // 0..127
    const int d0  = (threadIdx.x & 1) * 32;
    const size_t cbase = (size_t)(b * 32 + qb) * 4;

    float mv[4], lv[4];
    float M = MASK_S;
    #pragma unroll
    for (int ch = 0; ch < 4; ch++) if (ch < nc) {
        mv[ch] = ML[(cbase + ch) * 256 + qlo * 2];
        lv[ch] = ML[(cbase + ch) * 256 + qlo * 2 + 1];
        M = fmaxf(M, mv[ch]);
    }
    float L = 0.f, sc[4];
    #pragma unroll
    for (int ch = 0; ch < 4; ch++) if (ch < nc) {
        sc[ch] = __builtin_amdgcn_exp2f(mv[ch] - M);
        L += lv[ch] * sc[ch];
    }
    const float inv = 1.f / L;

    f32x4 acc[8];
    #pragma unroll
    for (int j = 0; j < 8; j++) { acc[j][0] = 0.f; acc[j][1] = 0.f; acc[j][2] = 0.f; acc[j][3] = 0.f; }
    #pragma unroll
    for (int ch = 0; ch < 4; ch++) if (ch < nc) {
        const float* bp = OP + (cbase + ch) * 8192 + (size_t)qlo * 64 + d0;
        #pragma unroll
        for (int j = 0; j < 8; j++) acc[j] += *(const f32x4*)(bp + j * 4) * sc[ch];
    }
    float* ob = out + (size_t)(b * SEQ + qb * 128 + qlo) * 64 + d0;
    #pragma unroll
    for (int j = 0; j < 8; j++) *(f32x4*)(ob + j * 4) = acc[j] * inv;
}

// ------------------------------------------------------------------- launch --
extern "C" void kernel_launch(void* const* d_in, const int* in_sizes, int n_in,
                              void* d_out, int out_size, void* d_ws, size_t ws_size,
                              hipStream_t stream)
{
    const float* x  = (const float*)d_in[0];
    const float* wQ = (const float*)d_in[1];
    const float* wK = (const float*)d_in[2];
    const float* wV = (const float*)d_in[3];
    float* out = (float*)d_out;

    // workspace: W 0.75MB + Q 8.4MB + KV 16.8MB + OP 33.5MB + ML 1MB ~= 60.5MB
    unsigned short* p   = (unsigned short*)d_ws;
    unsigned short* WHp = p; p += 192 * 1024;
    unsigned short* WLp = p; p += 192 * 1024;
    unsigned short* QHp = p; p += 8 * 4096 * 64;
    unsigned short* QLp = p; p += 8 * 4096 * 64;
    unsigned short* KVp = p; p += (size_t)8 * 64 * 16384;
    float* fp = (float*)p;
    float* OP = fp; fp += (size_t)8 * 32 * 4 * 8192;   // partial O
    float* ML = fp; fp += (size_t)8 * 32 * 4 * 256;    // (m,l)

    splitw_kernel<<<dim3(192), dim3(256), 0, stream>>>(wQ, wK, wV, WHp, WLp);
    proj_kernel<<<dim3(1024), dim3(256), 0, stream>>>(x, WHp, WLp, QHp, QLp, KVp);
    attn_kernel<<<dim3(2560), dim3(64), 0, stream>>>(QHp, QLp, KVp, OP, ML, out);
    combine_kernel<<<dim3(192), dim3(256), 0, stream>>>(OP, ML, out);
}